// Round 1
// baseline (206.245 us; speedup 1.0000x reference)
//
#include <hip/hip_runtime.h>
#include <hip/hip_bf16.h>

#define BATCH 2
#define SEQ   2048
#define DIM   1024
#define NH    16
#define HD    64
#define K_DIM 1024

typedef __attribute__((ext_vector_type(8))) short short8;
typedef __attribute__((ext_vector_type(4))) short short4v;
typedef __attribute__((ext_vector_type(4))) float f32x4;
typedef unsigned short ushort_t;

// fp32 -> bf16 bits, round-to-nearest-even
__device__ __forceinline__ unsigned short f2b(float x) {
    unsigned int u = __float_as_uint(x);
    u += 0x7FFFu + ((u >> 16) & 1u);
    return (unsigned short)(u >> 16);
}

// async global->LDS, 16B per lane; LDS dest = wave-uniform base + lane*16
#define ASYNC_COPY16(gp, lp) \
    __builtin_amdgcn_global_load_lds((const __attribute__((address_space(1))) void*)(gp), \
                                     (__attribute__((address_space(3))) void*)(lp), 16, 0, 0)

// ---------------------------------------------------------------------------
// Merged prep kernel: [0,1024) cast x; [1024,2560) transpose w_qkv;
// [2560,3072) transpose w_out.
// ---------------------------------------------------------------------------
__global__ __launch_bounds__(256)
void prep(const float* __restrict__ x, const float* __restrict__ w_qkv,
          const float* __restrict__ w_out, ushort_t* __restrict__ xb,
          ushort_t* __restrict__ wqb, ushort_t* __restrict__ wob)
{
    const int bid = blockIdx.x;
    if (bid < 1024) {
        constexpr int n4 = (BATCH * SEQ * DIM) / 4;
        int i = bid * 256 + threadIdx.x;
        for (; i < n4; i += 1024 * 256) {
            float4 v = ((const float4*)x)[i];
            short4v o;
            o[0] = (short)f2b(v.x); o[1] = (short)f2b(v.y);
            o[2] = (short)f2b(v.z); o[3] = (short)f2b(v.w);
            ((short4v*)xb)[i] = o;
        }
    } else {
        const int lane = threadIdx.x & 63;
        const float* src; ushort_t* dst; int N, job;
        if (bid < 2560) { src = w_qkv; dst = wqb; N = 3072; job = (bid - 1024) * 4 + (threadIdx.x >> 6); }
        else            { src = w_out; dst = wob; N = 1024; job = (bid - 2560) * 4 + (threadIdx.x >> 6); }
        const int jn = (N == 3072) ? (job % 48) : (job % 16);
        const int jk = (N == 3072) ? (job / 48) : (job / 16);
        const int n  = jn * 64 + lane;
        const int k0 = jk * 8;
        short8 o;
        #pragma unroll
        for (int j = 0; j < 8; ++j) o[j] = (short)f2b(src[(size_t)(k0 + j) * N + n]);
        *(short8*)(dst + (size_t)n * K_DIM + k0) = o;
    }
}

// ---------------------------------------------------------------------------
// 128x128 MFMA GEMM mainloop (R6 measured-best): BK=32, double-buffered LDS
// (8KB/buf/matrix), post-barrier prefetch, chunk-XOR swizzle.
// ---------------------------------------------------------------------------
__device__ __forceinline__ void gemm_stage(const ushort_t* __restrict__ Ag,
                                           const ushort_t* __restrict__ Bg,
                                           ushort_t* As, ushort_t* Bs,
                                           int k0, int w, int r0, int c0)
{
    ASYNC_COPY16(Ag + (size_t)r0 * K_DIM + k0 + c0 * 8,        As + w * 512);
    ASYNC_COPY16(Ag + (size_t)(64 + r0) * K_DIM + k0 + c0 * 8, As + w * 512 + 2048);
    ASYNC_COPY16(Bg + (size_t)r0 * K_DIM + k0 + c0 * 8,        Bs + w * 512);
    ASYNC_COPY16(Bg + (size_t)(64 + r0) * K_DIM + k0 + c0 * 8, Bs + w * 512 + 2048);
}

__device__ __forceinline__ void mfma_gemm_tile(
    const ushort_t* __restrict__ Ag, const ushort_t* __restrict__ Bg,
    ushort_t (&As)[2][128 * 32], ushort_t (&Bs)[2][128 * 32], f32x4 acc[4][4])
{
    const int t = threadIdx.x;
    const int w = t >> 6, lane = t & 63;
    const int qd = lane >> 4, cl = lane & 15;
    const int p0 = w * 64 + lane;
    const int r0 = p0 >> 2;
    const int c0 = (p0 & 3) ^ (r0 & 3);

    gemm_stage(Ag, Bg, As[0], Bs[0], 0, w, r0, c0);

    for (int kt = 0; kt < K_DIM / 32; ++kt) {
        const int cur = kt & 1;
        __syncthreads();
        if (kt + 1 < K_DIM / 32)
            gemm_stage(Ag, Bg, As[cur ^ 1], Bs[cur ^ 1], (kt + 1) * 32, w, r0, c0);

        short8 af[4], bfr[4];
        #pragma unroll
        for (int rt = 0; rt < 4; ++rt) {
            const int row = (w >> 1) * 64 + rt * 16 + cl;
            af[rt] = *(const short8*)(As[cur] + row * 32 + ((qd ^ (row & 3)) * 8));
        }
        #pragma unroll
        for (int ct = 0; ct < 4; ++ct) {
            const int col = (w & 1) * 64 + ct * 16 + cl;
            bfr[ct] = *(const short8*)(Bs[cur] + col * 32 + ((qd ^ (col & 3)) * 8));
        }
        #pragma unroll
        for (int rt = 0; rt < 4; ++rt)
            #pragma unroll
            for (int ct = 0; ct < 4; ++ct)
                acc[rt][ct] = __builtin_amdgcn_mfma_f32_16x16x32_bf16(
                    af[rt], bfr[ct], acc[rt][ct], 0, 0, 0);
    }
}

// ---------------------------------------------------------------------------
// GEMM1: qkv = xb @ wqb^T with fused RoPE + bf16 stores (d' = cl*4+ct perm).
// ---------------------------------------------------------------------------
__global__ __launch_bounds__(256, 3)
void gemm_qkv_mfma(const ushort_t* __restrict__ xb, const ushort_t* __restrict__ wqb,
                   ushort_t* __restrict__ qb, ushort_t* __restrict__ kb,
                   ushort_t* __restrict__ vt,
                   const float* __restrict__ cosb, const float* __restrict__ sinb)
{
    __shared__ __align__(16) ushort_t As[2][128 * 32];
    __shared__ __align__(16) ushort_t Bs[2][128 * 32];
    const int m0 = blockIdx.y * 128, n0 = blockIdx.x * 128;

    f32x4 acc[4][4];
    #pragma unroll
    for (int i = 0; i < 4; ++i)
        #pragma unroll
        for (int j = 0; j < 4; ++j)
            #pragma unroll
            for (int r = 0; r < 4; ++r) acc[i][j][r] = 0.f;

    mfma_gemm_tile(xb + (size_t)m0 * K_DIM, wqb + (size_t)n0 * K_DIM, As, Bs, acc);

    const int t = threadIdx.x, w = t >> 6, lane = t & 63;
    const int qd = lane >> 4, cl = lane & 15;
    const int b = m0 >> 11;
    const int lbase = (m0 & 2047) + (w >> 1) * 64;
    const int region = blockIdx.x >> 3;              // 0=q, 1=k, 2=v
    const int h = (blockIdx.x & 7) * 2 + (w & 1);

    if (region < 2) {
        ushort_t* dst = region ? kb : qb;
        const float sc = region ? 1.0f : 0.18033688011111234f;  // 0.125*log2(e)
        #pragma unroll
        for (int rt = 0; rt < 4; ++rt) {
            #pragma unroll
            for (int r = 0; r < 4; ++r) {
                const int l = lbase + rt * 16 + qd * 4 + r;
                const float c0 = cosb[l * HD + cl],      s0 = sinb[l * HD + cl];
                const float c1 = cosb[l * HD + 16 + cl], s1 = sinb[l * HD + 16 + cl];
                const float v0 = acc[rt][0][r] * c0 - acc[rt][2][r] * s0;
                const float v1 = acc[rt][1][r] * c1 - acc[rt][3][r] * s1;
                const float v2 = acc[rt][2][r] * c0 + acc[rt][0][r] * s0;
                const float v3 = acc[rt][3][r] * c1 + acc[rt][1][r] * s1;
                short4v o4;
                o4[0] = (short)f2b(v0 * sc);
                o4[1] = (short)f2b(v1 * sc);
                o4[2] = (short)f2b(v2 * sc);
                o4[3] = (short)f2b(v3 * sc);
                *(short4v*)(dst + (((size_t)b * NH + h) * SEQ + l) * HD + cl * 4) = o4;
            }
        }
    } else {
        #pragma unroll
        for (int rt = 0; rt < 4; ++rt)
            #pragma unroll
            for (int ct = 0; ct < 4; ++ct) {
                const int d = ct * 16 + cl;
                const int l = lbase + rt * 16 + qd * 4;
                short4v o4;
                #pragma unroll
                for (int r = 0; r < 4; ++r) o4[r] = (short)f2b(acc[rt][ct][r]);
                *(short4v*)(vt + (((size_t)b * NH + h) * HD + d) * SEQ + l) = o4;
            }
    }
}

// ---------------------------------------------------------------------------
// GEMM2: out = ob @ wob^T, 128x64 tiles (512 blocks -> 2 blocks/CU), BK=32
// dbuf staging, fp32 store.
// ---------------------------------------------------------------------------
__device__ __forceinline__ void go_stage(const ushort_t* __restrict__ Ag,
                                         const ushort_t* __restrict__ Bg,
                                         ushort_t* As, ushort_t* Bs,
                                         int k0, int w, int lane)
{
    #pragma unroll
    for (int j = 0; j < 2; ++j) {
        const int r = w * 32 + j * 16 + (lane >> 2);
        const int c = (lane & 3) ^ (r & 3);
        ASYNC_COPY16(Ag + (size_t)r * K_DIM + k0 + c * 8, As + (w * 128 + j * 64) * 8);
    }
    const int rb = w * 16 + (lane >> 2);
    const int cb = (lane & 3) ^ (rb & 3);
    ASYNC_COPY16(Bg + (size_t)rb * K_DIM + k0 + cb * 8, Bs + (w * 64) * 8);
}

__global__ __launch_bounds__(256, 3)
void gemm_out_mfma(const ushort_t* __restrict__ ob, const ushort_t* __restrict__ wob,
                   float* __restrict__ out)
{
    __shared__ __align__(16) ushort_t As[2][128 * 32];
    __shared__ __align__(16) ushort_t Bs[2][64 * 32];
    const int m0 = blockIdx.y * 128, n0 = blockIdx.x * 64;
    const int t = threadIdx.x;
    const int w = t >> 6, lane = t & 63;
    const int qd = lane >> 4, cl = lane & 15;
    const int wr = w >> 1, wc = w & 1;

    f32x4 acc[4][2];
    #pragma unroll
    for (int i = 0; i < 4; ++i)
        #pragma unroll
        for (int j = 0; j < 2; ++j)
            #pragma unroll
            for (int r = 0; r < 4; ++r) acc[i][j][r] = 0.f;

    const ushort_t* Ag = ob  + (size_t)m0 * K_DIM;
    const ushort_t* Bg = wob + (size_t)n0 * K_DIM;
    go_stage(Ag, Bg, As[0], Bs[0], 0, w, lane);

    for (int kt = 0; kt < K_DIM / 32; ++kt) {
        const int cur = kt & 1;
        __syncthreads();
        if (kt + 1 < K_DIM / 32)
            go_stage(Ag, Bg, As[cur ^ 1], Bs[cur ^ 1], (kt + 1) * 32, w, lane);

        short8 af[4], bfr[2];
        #pragma unroll
        for (int rt = 0; rt < 4; ++rt) {
            const int row = wr * 64 + rt * 16 + cl;
            af[rt] = *(const short8*)(As[cur] + row * 32 + ((qd ^ (row & 3)) * 8));
        }
        #pragma unroll
        for (int ct = 0; ct < 2; ++ct) {
            const int col = wc * 32 + ct * 16 + cl;
            bfr[ct] = *(const short8*)(Bs[cur] + col * 32 + ((qd ^ (col & 3)) * 8));
        }
        #pragma unroll
        for (int rt = 0; rt < 4; ++rt)
            #pragma unroll
            for (int ct = 0; ct < 2; ++ct)
                acc[rt][ct] = __builtin_amdgcn_mfma_f32_16x16x32_bf16(
                    af[rt], bfr[ct], acc[rt][ct], 0, 0, 0);
    }

    const int mbase = m0 + wr * 64, nbase = n0 + wc * 32;
    #pragma unroll
    for (int rt = 0; rt < 4; ++rt)
        #pragma unroll
        for (int ct = 0; ct < 2; ++ct)
            #pragma unroll
            for (int r = 0; r < 4; ++r)
                out[(size_t)(mbase + rt * 16 + qd * 4 + r) * DIM + nbase + ct * 16 + cl] =
                    acc[rt][ct][r];
}

// ---------------------------------------------------------------------------
// Flash attention v8: 64-query blocks (qt=32 -> 1024 blocks = 4 blocks/CU,
// 16 waves/CU vs v7's 8), each wave owns 16 queries (nt dim dropped). LDS
// 40KB (Ks 16 + Vs 16 + P 8) so exactly 4 blocks fit in 160KB/CU. Full-K per
// block, XCD-local grid (h fastest -> all 32 K/V-sharing blocks per (b,h) on
// one XCD), dbuf K/V staging with post-barrier prefetch, PV-deferral.
// ---------------------------------------------------------------------------
__global__ __launch_bounds__(256, 4)
void attn_mfma(const ushort_t* __restrict__ qb, const ushort_t* __restrict__ kb,
               const ushort_t* __restrict__ vt, ushort_t* __restrict__ ob)
{
    const int h = blockIdx.x;                 // fastest -> K/V sharers on one XCD
    const int b = blockIdx.y;
    const int qt = blockIdx.z;                // 0..31, 64 queries per block
    const int t = threadIdx.x;
    const int w = t >> 6, lane = t & 63;
    const int qd = lane >> 4, cl = lane & 15;
    constexpr int NT = SEQ / 64;              // 32 tiles, full range

    __shared__ __align__(16) ushort_t Ks[2][64 * 64];
    __shared__ __align__(16) ushort_t Vs[2][64 * 64];
    __shared__ __align__(16) ushort_t P[4][1024];   // 2KB per wave: 16q x 64k
    char* Pb = (char*)P[w];

    const size_t bh = (size_t)b * NH + h;
    const ushort_t* qbase = qb + (bh * SEQ + qt * 64 + w * 16) * HD;
    const ushort_t* kbase = kb + bh * SEQ * HD;
    const ushort_t* vbase = vt + bh * (size_t)HD * SEQ;

    const int p0 = w * 128 + lane;
    const int r0a = p0 >> 3,  c0a = (p0 & 7) ^ (r0a & 7);
    const int p1 = p0 + 64;
    const int r1a = p1 >> 3,  c1a = (p1 & 7) ^ (r1a & 7);
    const int ldsoff0 = (w * 128) * 8;
    const int ldsoff1 = (w * 128 + 64) * 8;

    short8 qf[2];
    #pragma unroll
    for (int kh = 0; kh < 2; ++kh)
        qf[kh] = *(const short8*)(qbase + cl * HD + kh * 32 + qd * 8);

    f32x4 oaccT[4];
    float l_part = 0.f;
    #pragma unroll
    for (int dt = 0; dt < 4; ++dt)
        #pragma unroll
        for (int r = 0; r < 4; ++r) oaccT[dt][r] = 0.f;

    // deferred-PV state (zeros make the kt==0 PV a no-op)
    short8 pf_prev[2], vf_prev[4][2];
    #pragma unroll
    for (int kh = 0; kh < 2; ++kh)
        #pragma unroll
        for (int e = 0; e < 8; ++e) pf_prev[kh][e] = 0;
    #pragma unroll
    for (int dt = 0; dt < 4; ++dt)
        #pragma unroll
        for (int kh = 0; kh < 2; ++kh)
            #pragma unroll
            for (int e = 0; e < 8; ++e) vf_prev[dt][kh][e] = 0;

    {   // stage tile 0 into buffer 0
        ASYNC_COPY16(kbase + (size_t)r0a * HD + c0a * 8,            (ushort_t*)Ks[0] + ldsoff0);
        ASYNC_COPY16(kbase + (size_t)r1a * HD + c1a * 8,            (ushort_t*)Ks[0] + ldsoff1);
        ASYNC_COPY16(vbase + (size_t)r0a * SEQ + c0a * 8,           (ushort_t*)Vs[0] + ldsoff0);
        ASYNC_COPY16(vbase + (size_t)r1a * SEQ + c1a * 8,           (ushort_t*)Vs[0] + ldsoff1);
    }

    for (int kt = 0; kt < NT; ++kt) {
        const int cur = kt & 1;
        __syncthreads();
        if (kt + 1 < NT) {
            const int g = kt + 1;
            ASYNC_COPY16(kbase + (size_t)(g * 64 + r0a) * HD + c0a * 8, (ushort_t*)Ks[cur ^ 1] + ldsoff0);
            ASYNC_COPY16(kbase + (size_t)(g * 64 + r1a) * HD + c1a * 8, (ushort_t*)Ks[cur ^ 1] + ldsoff1);
            ASYNC_COPY16(vbase + (size_t)r0a * SEQ + g * 64 + c0a * 8,  (ushort_t*)Vs[cur ^ 1] + ldsoff0);
            ASYNC_COPY16(vbase + (size_t)r1a * SEQ + g * 64 + c1a * 8,  (ushort_t*)Vs[cur ^ 1] + ldsoff1);
        }

        short8 kf[4][2], vf[4][2];
        #pragma unroll
        for (int mt = 0; mt < 4; ++mt)
            #pragma unroll
            for (int kh = 0; kh < 2; ++kh)
                kf[mt][kh] = *(const short8*)(Ks[cur] + ((mt * 16 + cl) * 8 + ((kh * 4 + qd) ^ (cl & 7))) * 8);
        #pragma unroll
        for (int dt = 0; dt < 4; ++dt)
            #pragma unroll
            for (int kh = 0; kh < 2; ++kh)
                vf[dt][kh] = *(const short8*)(Vs[cur] + ((dt * 16 + cl) * 8 + ((kh * 4 + qd) ^ (cl & 7))) * 8);

        // ---- S^T = K Q^T  (16 k-rows x 16 queries per wave, 64 k total)
        f32x4 s[4];
        #pragma unroll
        for (int mt = 0; mt < 4; ++mt)
            #pragma unroll
            for (int r = 0; r < 4; ++r) s[mt][r] = 0.f;
        #pragma unroll
        for (int kh = 0; kh < 2; ++kh)
            #pragma unroll
            for (int mt = 0; mt < 4; ++mt)
                s[mt] = __builtin_amdgcn_mfma_f32_16x16x32_bf16(
                    kf[mt][kh], qf[kh], s[mt], 0, 0, 0);

        // ---- deferred O^T += V^T(kt-1) P^T(kt-1)  (registers only)
        #pragma unroll
        for (int kh = 0; kh < 2; ++kh)
            #pragma unroll
            for (int dt = 0; dt < 4; ++dt)
                oaccT[dt] = __builtin_amdgcn_mfma_f32_16x16x32_bf16(
                    vf_prev[dt][kh], pf_prev[kh], oaccT[dt], 0, 0, 0);

        // ---- exp2 + pack + P^T write
        #pragma unroll
        for (int mt = 0; mt < 4; ++mt) {
            const float e0 = __builtin_amdgcn_exp2f(s[mt][0]);
            const float e1 = __builtin_amdgcn_exp2f(s[mt][1]);
            const float e2 = __builtin_amdgcn_exp2f(s[mt][2]);
            const float e3 = __builtin_amdgcn_exp2f(s[mt][3]);
            l_part += (e0 + e1) + (e2 + e3);
            union { __hip_bfloat162 h2[2]; unsigned long long u64; } pk;
            pk.h2[0] = __float22bfloat162_rn(make_float2(e0, e1));
            pk.h2[1] = __float22bfloat162_rn(make_float2(e2, e3));
            const int g = (mt * 2 + (qd >> 1)) ^ (cl & 7);
            *(unsigned long long*)(Pb + cl * 128 + g * 16 + (qd & 1) * 8) = pk.u64;
        }
        __builtin_amdgcn_wave_barrier();

        // ---- read P(kt) fragments for next iteration's deferred PV
        #pragma unroll
        for (int kh = 0; kh < 2; ++kh)
            pf_prev[kh] = *(const short8*)(Pb + cl * 128 + (((kh * 4 + qd) ^ (cl & 7)) * 16));
        #pragma unroll
        for (int dt = 0; dt < 4; ++dt)
            #pragma unroll
            for (int kh = 0; kh < 2; ++kh)
                vf_prev[dt][kh] = vf[dt][kh];
    }

    // tail PV for the last tile
    #pragma unroll
    for (int kh = 0; kh < 2; ++kh)
        #pragma unroll
        for (int dt = 0; dt < 4; ++dt)
            oaccT[dt] = __builtin_amdgcn_mfma_f32_16x16x32_bf16(
                vf_prev[dt][kh], pf_prev[kh], oaccT[dt], 0, 0, 0);

    // ---- epilogue: complete l -> normalize -> bf16 ob[b][query][h*64+d]
    {
        float l = l_part;
        l += __shfl_xor(l, 16);
        l += __shfl_xor(l, 32);
        const float inv = 1.0f / l;
        const int query = qt * 64 + w * 16 + cl;
        ushort_t* op = ob + ((size_t)b * SEQ + query) * DIM + h * HD;
        #pragma unroll
        for (int dt = 0; dt < 4; ++dt) {
            short4v o4;
            #pragma unroll
            for (int r = 0; r < 4; ++r) o4[r] = (short)f2b(oaccT[dt][r] * inv);
            *(short4v*)(op + dt * 16 + qd * 4) = o4;
        }
    }
}

// ---------------------------------------------------------------------------
extern "C" void kernel_launch(void* const* d_in, const int* in_sizes, int n_in,
                              void* d_out, int out_size, void* d_ws, size_t ws_size,
                              hipStream_t stream)
{
    const float* x     = (const float*)d_in[0];
    const float* cosb  = (const float*)d_in[1];
    const float* sinb  = (const float*)d_in[2];
    const float* w_qkv = (const float*)d_in[3];
    const float* w_out = (const float*)d_in[4];
    float* out = (float*)d_out;

    // workspace layout (peak 48MB, no aliasing hazards):
    //  [0,8)   qb   [8,16) kb   [16,24) vt   [24,26) wob
    //  [26,34) ob   [34,42) xb  [42,48) wqb
    constexpr size_t MB = 1u << 20;
    char* ws = (char*)d_ws;
    ushort_t* qb  = (ushort_t*)(ws);
    ushort_t* kb  = (ushort_t*)(ws + 8 * MB);
    ushort_t* vt  = (ushort_t*)(ws + 16 * MB);
    ushort_t* wob = (ushort_t*)(ws + 24 * MB);
    ushort_t* ob  = (ushort_t*)(ws + 26 * MB);
    ushort_t* xb  = (ushort_t*)(ws + 34 * MB);
    ushort_t* wqb = (ushort_t*)(ws + 42 * MB);

    prep<<<3072, 256, 0, stream>>>(x, w_qkv, w_out, xb, wqb, wob);
    gemm_qkv_mfma<<<dim3(24, 32), 256, 0, stream>>>(xb, wqb, qb, kb, vt, cosb, sinb);
    attn_mfma<<<dim3(16, 2, 32), 256, 0, stream>>>(qb, kb, vt, ob);
    gemm_out_mfma<<<dim3(16, 32), 256, 0, stream>>>(ob, wob, out);
}

// Round 2
// 191.046 us; speedup vs baseline: 1.0796x; 1.0796x over previous
//
#include <hip/hip_runtime.h>
#include <hip/hip_bf16.h>

#define BATCH 2
#define SEQ   2048
#define DIM   1024
#define NH    16
#define HD    64
#define K_DIM 1024

typedef __attribute__((ext_vector_type(8))) short short8;
typedef __attribute__((ext_vector_type(4))) short short4v;
typedef __attribute__((ext_vector_type(4))) float f32x4;
typedef unsigned short ushort_t;

// fp32 -> bf16 bits, round-to-nearest-even
__device__ __forceinline__ unsigned short f2b(float x) {
    unsigned int u = __float_as_uint(x);
    u += 0x7FFFu + ((u >> 16) & 1u);
    return (unsigned short)(u >> 16);
}

// async global->LDS, 16B per lane; LDS dest = wave-uniform base + lane*16
#define ASYNC_COPY16(gp, lp) \
    __builtin_amdgcn_global_load_lds((const __attribute__((address_space(1))) void*)(gp), \
                                     (__attribute__((address_space(3))) void*)(lp), 16, 0, 0)

// ---------------------------------------------------------------------------
// Merged prep kernel: [0,1024) cast x; [1024,2560) transpose w_qkv;
// [2560,3072) transpose w_out.
// ---------------------------------------------------------------------------
__global__ __launch_bounds__(256)
void prep(const float* __restrict__ x, const float* __restrict__ w_qkv,
          const float* __restrict__ w_out, ushort_t* __restrict__ xb,
          ushort_t* __restrict__ wqb, ushort_t* __restrict__ wob)
{
    const int bid = blockIdx.x;
    if (bid < 1024) {
        constexpr int n4 = (BATCH * SEQ * DIM) / 4;
        int i = bid * 256 + threadIdx.x;
        for (; i < n4; i += 1024 * 256) {
            float4 v = ((const float4*)x)[i];
            short4v o;
            o[0] = (short)f2b(v.x); o[1] = (short)f2b(v.y);
            o[2] = (short)f2b(v.z); o[3] = (short)f2b(v.w);
            ((short4v*)xb)[i] = o;
        }
    } else {
        const int lane = threadIdx.x & 63;
        const float* src; ushort_t* dst; int N, job;
        if (bid < 2560) { src = w_qkv; dst = wqb; N = 3072; job = (bid - 1024) * 4 + (threadIdx.x >> 6); }
        else            { src = w_out; dst = wob; N = 1024; job = (bid - 2560) * 4 + (threadIdx.x >> 6); }
        const int jn = (N == 3072) ? (job % 48) : (job % 16);
        const int jk = (N == 3072) ? (job / 48) : (job / 16);
        const int n  = jn * 64 + lane;
        const int k0 = jk * 8;
        short8 o;
        #pragma unroll
        for (int j = 0; j < 8; ++j) o[j] = (short)f2b(src[(size_t)(k0 + j) * N + n]);
        *(short8*)(dst + (size_t)n * K_DIM + k0) = o;
    }
}

// ---------------------------------------------------------------------------
// 128x128 MFMA GEMM mainloop (R6 measured-best): BK=32, double-buffered LDS
// (8KB/buf/matrix), post-barrier prefetch, chunk-XOR swizzle.
// ---------------------------------------------------------------------------
__device__ __forceinline__ void gemm_stage(const ushort_t* __restrict__ Ag,
                                           const ushort_t* __restrict__ Bg,
                                           ushort_t* As, ushort_t* Bs,
                                           int k0, int w, int r0, int c0)
{
    ASYNC_COPY16(Ag + (size_t)r0 * K_DIM + k0 + c0 * 8,        As + w * 512);
    ASYNC_COPY16(Ag + (size_t)(64 + r0) * K_DIM + k0 + c0 * 8, As + w * 512 + 2048);
    ASYNC_COPY16(Bg + (size_t)r0 * K_DIM + k0 + c0 * 8,        Bs + w * 512);
    ASYNC_COPY16(Bg + (size_t)(64 + r0) * K_DIM + k0 + c0 * 8, Bs + w * 512 + 2048);
}

__device__ __forceinline__ void mfma_gemm_tile(
    const ushort_t* __restrict__ Ag, const ushort_t* __restrict__ Bg,
    ushort_t (&As)[2][128 * 32], ushort_t (&Bs)[2][128 * 32], f32x4 acc[4][4])
{
    const int t = threadIdx.x;
    const int w = t >> 6, lane = t & 63;
    const int qd = lane >> 4, cl = lane & 15;
    const int p0 = w * 64 + lane;
    const int r0 = p0 >> 2;
    const int c0 = (p0 & 3) ^ (r0 & 3);

    gemm_stage(Ag, Bg, As[0], Bs[0], 0, w, r0, c0);

    for (int kt = 0; kt < K_DIM / 32; ++kt) {
        const int cur = kt & 1;
        __syncthreads();
        if (kt + 1 < K_DIM / 32)
            gemm_stage(Ag, Bg, As[cur ^ 1], Bs[cur ^ 1], (kt + 1) * 32, w, r0, c0);

        short8 af[4], bfr[4];
        #pragma unroll
        for (int rt = 0; rt < 4; ++rt) {
            const int row = (w >> 1) * 64 + rt * 16 + cl;
            af[rt] = *(const short8*)(As[cur] + row * 32 + ((qd ^ (row & 3)) * 8));
        }
        #pragma unroll
        for (int ct = 0; ct < 4; ++ct) {
            const int col = (w & 1) * 64 + ct * 16 + cl;
            bfr[ct] = *(const short8*)(Bs[cur] + col * 32 + ((qd ^ (col & 3)) * 8));
        }
        #pragma unroll
        for (int rt = 0; rt < 4; ++rt)
            #pragma unroll
            for (int ct = 0; ct < 4; ++ct)
                acc[rt][ct] = __builtin_amdgcn_mfma_f32_16x16x32_bf16(
                    af[rt], bfr[ct], acc[rt][ct], 0, 0, 0);
    }
}

// ---------------------------------------------------------------------------
// GEMM1: qkv = xb @ wqb^T with fused RoPE + bf16 stores (d' = cl*4+ct perm).
// ---------------------------------------------------------------------------
__global__ __launch_bounds__(256, 3)
void gemm_qkv_mfma(const ushort_t* __restrict__ xb, const ushort_t* __restrict__ wqb,
                   ushort_t* __restrict__ qb, ushort_t* __restrict__ kb,
                   ushort_t* __restrict__ vt,
                   const float* __restrict__ cosb, const float* __restrict__ sinb)
{
    __shared__ __align__(16) ushort_t As[2][128 * 32];
    __shared__ __align__(16) ushort_t Bs[2][128 * 32];
    const int m0 = blockIdx.y * 128, n0 = blockIdx.x * 128;

    f32x4 acc[4][4];
    #pragma unroll
    for (int i = 0; i < 4; ++i)
        #pragma unroll
        for (int j = 0; j < 4; ++j)
            #pragma unroll
            for (int r = 0; r < 4; ++r) acc[i][j][r] = 0.f;

    mfma_gemm_tile(xb + (size_t)m0 * K_DIM, wqb + (size_t)n0 * K_DIM, As, Bs, acc);

    const int t = threadIdx.x, w = t >> 6, lane = t & 63;
    const int qd = lane >> 4, cl = lane & 15;
    const int b = m0 >> 11;
    const int lbase = (m0 & 2047) + (w >> 1) * 64;
    const int region = blockIdx.x >> 3;              // 0=q, 1=k, 2=v
    const int h = (blockIdx.x & 7) * 2 + (w & 1);

    if (region < 2) {
        ushort_t* dst = region ? kb : qb;
        const float sc = region ? 1.0f : 0.18033688011111234f;  // 0.125*log2(e)
        #pragma unroll
        for (int rt = 0; rt < 4; ++rt) {
            #pragma unroll
            for (int r = 0; r < 4; ++r) {
                const int l = lbase + rt * 16 + qd * 4 + r;
                const float c0 = cosb[l * HD + cl],      s0 = sinb[l * HD + cl];
                const float c1 = cosb[l * HD + 16 + cl], s1 = sinb[l * HD + 16 + cl];
                const float v0 = acc[rt][0][r] * c0 - acc[rt][2][r] * s0;
                const float v1 = acc[rt][1][r] * c1 - acc[rt][3][r] * s1;
                const float v2 = acc[rt][2][r] * c0 + acc[rt][0][r] * s0;
                const float v3 = acc[rt][3][r] * c1 + acc[rt][1][r] * s1;
                short4v o4;
                o4[0] = (short)f2b(v0 * sc);
                o4[1] = (short)f2b(v1 * sc);
                o4[2] = (short)f2b(v2 * sc);
                o4[3] = (short)f2b(v3 * sc);
                *(short4v*)(dst + (((size_t)b * NH + h) * SEQ + l) * HD + cl * 4) = o4;
            }
        }
    } else {
        #pragma unroll
        for (int rt = 0; rt < 4; ++rt)
            #pragma unroll
            for (int ct = 0; ct < 4; ++ct) {
                const int d = ct * 16 + cl;
                const int l = lbase + rt * 16 + qd * 4;
                short4v o4;
                #pragma unroll
                for (int r = 0; r < 4; ++r) o4[r] = (short)f2b(acc[rt][ct][r]);
                *(short4v*)(vt + (((size_t)b * NH + h) * HD + d) * SEQ + l) = o4;
            }
    }
}

// ---------------------------------------------------------------------------
// GEMM2: out = ob @ wob^T, 128x64 tiles (512 blocks -> 2 blocks/CU), BK=32
// dbuf staging, fp32 store.
// ---------------------------------------------------------------------------
__device__ __forceinline__ void go_stage(const ushort_t* __restrict__ Ag,
                                         const ushort_t* __restrict__ Bg,
                                         ushort_t* As, ushort_t* Bs,
                                         int k0, int w, int lane)
{
    #pragma unroll
    for (int j = 0; j < 2; ++j) {
        const int r = w * 32 + j * 16 + (lane >> 2);
        const int c = (lane & 3) ^ (r & 3);
        ASYNC_COPY16(Ag + (size_t)r * K_DIM + k0 + c * 8, As + (w * 128 + j * 64) * 8);
    }
    const int rb = w * 16 + (lane >> 2);
    const int cb = (lane & 3) ^ (rb & 3);
    ASYNC_COPY16(Bg + (size_t)rb * K_DIM + k0 + cb * 8, Bs + (w * 64) * 8);
}

__global__ __launch_bounds__(256, 3)
void gemm_out_mfma(const ushort_t* __restrict__ ob, const ushort_t* __restrict__ wob,
                   float* __restrict__ out)
{
    __shared__ __align__(16) ushort_t As[2][128 * 32];
    __shared__ __align__(16) ushort_t Bs[2][64 * 32];
    const int m0 = blockIdx.y * 128, n0 = blockIdx.x * 64;
    const int t = threadIdx.x;
    const int w = t >> 6, lane = t & 63;
    const int qd = lane >> 4, cl = lane & 15;
    const int wr = w >> 1, wc = w & 1;

    f32x4 acc[4][2];
    #pragma unroll
    for (int i = 0; i < 4; ++i)
        #pragma unroll
        for (int j = 0; j < 2; ++j)
            #pragma unroll
            for (int r = 0; r < 4; ++r) acc[i][j][r] = 0.f;

    const ushort_t* Ag = ob  + (size_t)m0 * K_DIM;
    const ushort_t* Bg = wob + (size_t)n0 * K_DIM;
    go_stage(Ag, Bg, As[0], Bs[0], 0, w, lane);

    for (int kt = 0; kt < K_DIM / 32; ++kt) {
        const int cur = kt & 1;
        __syncthreads();
        if (kt + 1 < K_DIM / 32)
            go_stage(Ag, Bg, As[cur ^ 1], Bs[cur ^ 1], (kt + 1) * 32, w, lane);

        short8 af[4], bfr[2];
        #pragma unroll
        for (int rt = 0; rt < 4; ++rt) {
            const int row = wr * 64 + rt * 16 + cl;
            af[rt] = *(const short8*)(As[cur] + row * 32 + ((qd ^ (row & 3)) * 8));
        }
        #pragma unroll
        for (int ct = 0; ct < 2; ++ct) {
            const int col = wc * 32 + ct * 16 + cl;
            bfr[ct] = *(const short8*)(Bs[cur] + col * 32 + ((qd ^ (col & 3)) * 8));
        }
        #pragma unroll
        for (int rt = 0; rt < 4; ++rt)
            #pragma unroll
            for (int ct = 0; ct < 2; ++ct)
                acc[rt][ct] = __builtin_amdgcn_mfma_f32_16x16x32_bf16(
                    af[rt], bfr[ct], acc[rt][ct], 0, 0, 0);
    }

    const int mbase = m0 + wr * 64, nbase = n0 + wc * 32;
    #pragma unroll
    for (int rt = 0; rt < 4; ++rt)
        #pragma unroll
        for (int ct = 0; ct < 2; ++ct)
            #pragma unroll
            for (int r = 0; r < 4; ++r)
                out[(size_t)(mbase + rt * 16 + qd * 4 + r) * DIM + nbase + ct * 16 + cl] =
                    acc[rt][ct][r];
}

// ---------------------------------------------------------------------------
// Flash attention v9: back to 128-query blocks (32 q/wave, nt=2) for 2x K/V
// LDS-read amortization, but the P LDS round-trip is replaced by in-register
// redistribution: per (kh,i) one v_permlane32_swap + one v_permlane16_swap
// moves the packed bf16 S-pairs into the exact PV B-fragment layout
// (k = kh*32 + qd*8 + j), verified equivalent to the old LDS encoding.
// LDS = 32KB (K/V dbuf only). Register-level PV-deferral retained so PV(kt-1)
// overlaps exp2/pack(kt). Grid 512 = 2 blocks/CU (grid-limited, so
// launch_bounds(256,2) -> VGPR headroom, no spills).
// ---------------------------------------------------------------------------
__global__ __launch_bounds__(256, 2)
void attn_mfma(const ushort_t* __restrict__ qb, const ushort_t* __restrict__ kb,
               const ushort_t* __restrict__ vt, ushort_t* __restrict__ ob)
{
    const int h = blockIdx.x;                 // fastest -> K/V sharers on one XCD
    const int b = blockIdx.y;
    const int qt = blockIdx.z;                // 0..15, 128 queries per block
    const int t = threadIdx.x;
    const int w = t >> 6, lane = t & 63;
    const int qd = lane >> 4, cl = lane & 15;
    constexpr int NT = SEQ / 64;              // 32 tiles, full range

    __shared__ __align__(16) ushort_t Ks[2][64 * 64];
    __shared__ __align__(16) ushort_t Vs[2][64 * 64];

    const size_t bh = (size_t)b * NH + h;
    const ushort_t* qbase = qb + (bh * SEQ + qt * 128 + w * 32) * HD;
    const ushort_t* kbase = kb + bh * SEQ * HD;
    const ushort_t* vbase = vt + bh * (size_t)HD * SEQ;

    const int p0 = w * 128 + lane;
    const int r0a = p0 >> 3,  c0a = (p0 & 7) ^ (r0a & 7);
    const int p1 = p0 + 64;
    const int r1a = p1 >> 3,  c1a = (p1 & 7) ^ (r1a & 7);
    const int ldsoff0 = (w * 128) * 8;
    const int ldsoff1 = (w * 128 + 64) * 8;

    short8 qf[2][2];
    #pragma unroll
    for (int nt = 0; nt < 2; ++nt)
        #pragma unroll
        for (int kh = 0; kh < 2; ++kh)
            qf[nt][kh] = *(const short8*)(qbase + (nt * 16 + cl) * HD + kh * 32 + qd * 8);

    f32x4 oaccT[4][2];
    float l_part[2] = {0.f, 0.f};
    #pragma unroll
    for (int dt = 0; dt < 4; ++dt)
        #pragma unroll
        for (int nt = 0; nt < 2; ++nt)
            #pragma unroll
            for (int r = 0; r < 4; ++r) oaccT[dt][nt][r] = 0.f;

    // deferred-PV state (zeros make the kt==0 PV a no-op)
    short8 pf_prev[2][2], vf_prev[4][2];
    #pragma unroll
    for (int nt = 0; nt < 2; ++nt)
        #pragma unroll
        for (int kh = 0; kh < 2; ++kh)
            #pragma unroll
            for (int e = 0; e < 8; ++e) pf_prev[nt][kh][e] = 0;
    #pragma unroll
    for (int dt = 0; dt < 4; ++dt)
        #pragma unroll
        for (int kh = 0; kh < 2; ++kh)
            #pragma unroll
            for (int e = 0; e < 8; ++e) vf_prev[dt][kh][e] = 0;

    {   // stage tile 0 into buffer 0
        ASYNC_COPY16(kbase + (size_t)r0a * HD + c0a * 8,            (ushort_t*)Ks[0] + ldsoff0);
        ASYNC_COPY16(kbase + (size_t)r1a * HD + c1a * 8,            (ushort_t*)Ks[0] + ldsoff1);
        ASYNC_COPY16(vbase + (size_t)r0a * SEQ + c0a * 8,           (ushort_t*)Vs[0] + ldsoff0);
        ASYNC_COPY16(vbase + (size_t)r1a * SEQ + c1a * 8,           (ushort_t*)Vs[0] + ldsoff1);
    }

    for (int kt = 0; kt < NT; ++kt) {
        const int cur = kt & 1;
        __syncthreads();
        if (kt + 1 < NT) {
            const int g = kt + 1;
            ASYNC_COPY16(kbase + (size_t)(g * 64 + r0a) * HD + c0a * 8, (ushort_t*)Ks[cur ^ 1] + ldsoff0);
            ASYNC_COPY16(kbase + (size_t)(g * 64 + r1a) * HD + c1a * 8, (ushort_t*)Ks[cur ^ 1] + ldsoff1);
            ASYNC_COPY16(vbase + (size_t)r0a * SEQ + g * 64 + c0a * 8,  (ushort_t*)Vs[cur ^ 1] + ldsoff0);
            ASYNC_COPY16(vbase + (size_t)r1a * SEQ + g * 64 + c1a * 8,  (ushort_t*)Vs[cur ^ 1] + ldsoff1);
        }

        short8 kf[4][2], vf[4][2];
        #pragma unroll
        for (int mt = 0; mt < 4; ++mt)
            #pragma unroll
            for (int kh = 0; kh < 2; ++kh)
                kf[mt][kh] = *(const short8*)(Ks[cur] + ((mt * 16 + cl) * 8 + ((kh * 4 + qd) ^ (cl & 7))) * 8);
        #pragma unroll
        for (int dt = 0; dt < 4; ++dt)
            #pragma unroll
            for (int kh = 0; kh < 2; ++kh)
                vf[dt][kh] = *(const short8*)(Vs[cur] + ((dt * 16 + cl) * 8 + ((kh * 4 + qd) ^ (cl & 7))) * 8);

        // ---- S^T = K Q^T  (64 k-rows x 32 queries per wave)
        f32x4 s[4][2];
        #pragma unroll
        for (int mt = 0; mt < 4; ++mt)
            #pragma unroll
            for (int nt = 0; nt < 2; ++nt)
                #pragma unroll
                for (int r = 0; r < 4; ++r) s[mt][nt][r] = 0.f;
        __builtin_amdgcn_s_setprio(1);
        #pragma unroll
        for (int kh = 0; kh < 2; ++kh)
            #pragma unroll
            for (int mt = 0; mt < 4; ++mt)
                #pragma unroll
                for (int nt = 0; nt < 2; ++nt)
                    s[mt][nt] = __builtin_amdgcn_mfma_f32_16x16x32_bf16(
                        kf[mt][kh], qf[nt][kh], s[mt][nt], 0, 0, 0);

        // ---- deferred O^T += V^T(kt-1) P^T(kt-1)  (registers only)
        #pragma unroll
        for (int kh = 0; kh < 2; ++kh)
            #pragma unroll
            for (int dt = 0; dt < 4; ++dt)
                #pragma unroll
                for (int nt = 0; nt < 2; ++nt)
                    oaccT[dt][nt] = __builtin_amdgcn_mfma_f32_16x16x32_bf16(
                        vf_prev[dt][kh], pf_prev[nt][kh], oaccT[dt][nt], 0, 0, 0);
        __builtin_amdgcn_s_setprio(0);

        // ---- exp2 + pack + in-register P redistribution (no LDS)
        // src: s[mt][nt][r] = P[k = mt*16+qd*4+r][q]; pack pairs -> wr[mt][i]
        // dst: pf[nt][kh] elem j = P[k = kh*32+qd*8+j][q] (B-fragment layout)
        // per (kh,i): permlane32_swap then permlane16_swap yields words
        // {i, 2+i} of pf[kh]. Verified element-wise vs the old LDS encoding.
        #pragma unroll
        for (int nt = 0; nt < 2; ++nt) {
            unsigned int wr[4][2];
            #pragma unroll
            for (int mt = 0; mt < 4; ++mt) {
                const float e0 = __builtin_amdgcn_exp2f(s[mt][nt][0]);
                const float e1 = __builtin_amdgcn_exp2f(s[mt][nt][1]);
                const float e2 = __builtin_amdgcn_exp2f(s[mt][nt][2]);
                const float e3 = __builtin_amdgcn_exp2f(s[mt][nt][3]);
                l_part[nt] += (e0 + e1) + (e2 + e3);
                union { __hip_bfloat162 h2; unsigned int u; } pk0, pk1;
                pk0.h2 = __float22bfloat162_rn(make_float2(e0, e1));
                pk1.h2 = __float22bfloat162_rn(make_float2(e2, e3));
                wr[mt][0] = pk0.u;
                wr[mt][1] = pk1.u;
            }
            #pragma unroll
            for (int kh = 0; kh < 2; ++kh) {
                union { unsigned int u[4]; short8 s8; } pu;
                #pragma unroll
                for (int i = 0; i < 2; ++i) {
                    unsigned int a  = wr[2 * kh][i];
                    unsigned int bb = wr[2 * kh + 1][i];
                    asm("v_permlane32_swap_b32 %0, %1" : "+v"(a), "+v"(bb));
                    asm("v_permlane16_swap_b32 %0, %1" : "+v"(a), "+v"(bb));
                    pu.u[i]     = a;   // word W=i   (src qd even half)
                    pu.u[2 + i] = bb;  // word W=2+i (src qd odd half)
                }
                pf_prev[nt][kh] = pu.s8;
            }
        }
        #pragma unroll
        for (int dt = 0; dt < 4; ++dt)
            #pragma unroll
            for (int kh = 0; kh < 2; ++kh)
                vf_prev[dt][kh] = vf[dt][kh];
    }

    // tail PV for the last tile
    #pragma unroll
    for (int kh = 0; kh < 2; ++kh)
        #pragma unroll
        for (int dt = 0; dt < 4; ++dt)
            #pragma unroll
            for (int nt = 0; nt < 2; ++nt)
                oaccT[dt][nt] = __builtin_amdgcn_mfma_f32_16x16x32_bf16(
                    vf_prev[dt][kh], pf_prev[nt][kh], oaccT[dt][nt], 0, 0, 0);

    // ---- epilogue: complete l -> normalize -> bf16 ob[b][query][h*64+d]
    #pragma unroll
    for (int nt = 0; nt < 2; ++nt) {
        float l = l_part[nt];
        l += __shfl_xor(l, 16);
        l += __shfl_xor(l, 32);
        const float inv = 1.0f / l;
        const int query = qt * 128 + w * 32 + nt * 16 + cl;
        ushort_t* op = ob + ((size_t)b * SEQ + query) * DIM + h * HD;
        #pragma unroll
        for (int dt = 0; dt < 4; ++dt) {
            short4v o4;
            #pragma unroll
            for (int r = 0; r < 4; ++r) o4[r] = (short)f2b(oaccT[dt][nt][r] * inv);
            *(short4v*)(op + dt * 16 + qd * 4) = o4;
        }
    }
}

// ---------------------------------------------------------------------------
extern "C" void kernel_launch(void* const* d_in, const int* in_sizes, int n_in,
                              void* d_out, int out_size, void* d_ws, size_t ws_size,
                              hipStream_t stream)
{
    const float* x     = (const float*)d_in[0];
    const float* cosb  = (const float*)d_in[1];
    const float* sinb  = (const float*)d_in[2];
    const float* w_qkv = (const float*)d_in[3];
    const float* w_out = (const float*)d_in[4];
    float* out = (float*)d_out;

    // workspace layout (peak 48MB, no aliasing hazards):
    //  [0,8)   qb   [8,16) kb   [16,24) vt   [24,26) wob
    //  [26,34) ob   [34,42) xb  [42,48) wqb
    constexpr size_t MB = 1u << 20;
    char* ws = (char*)d_ws;
    ushort_t* qb  = (ushort_t*)(ws);
    ushort_t* kb  = (ushort_t*)(ws + 8 * MB);
    ushort_t* vt  = (ushort_t*)(ws + 16 * MB);
    ushort_t* wob = (ushort_t*)(ws + 24 * MB);
    ushort_t* ob  = (ushort_t*)(ws + 26 * MB);
    ushort_t* xb  = (ushort_t*)(ws + 34 * MB);
    ushort_t* wqb = (ushort_t*)(ws + 42 * MB);

    prep<<<3072, 256, 0, stream>>>(x, w_qkv, w_out, xb, wqb, wob);
    gemm_qkv_mfma<<<dim3(24, 32), 256, 0, stream>>>(xb, wqb, qb, kb, vt, cosb, sinb);
    attn_mfma<<<dim3(16, 2, 16), 256, 0, stream>>>(qb, kb, vt, ob);
    gemm_out_mfma<<<dim3(16, 32), 256, 0, stream>>>(ob, wob, out);
}

// Round 3
// 190.958 us; speedup vs baseline: 1.0801x; 1.0005x over previous
//
#include <hip/hip_runtime.h>
#include <hip/hip_bf16.h>

#define BATCH 2
#define SEQ   2048
#define DIM   1024
#define NH    16
#define HD    64
#define K_DIM 1024

typedef __attribute__((ext_vector_type(8))) short short8;
typedef __attribute__((ext_vector_type(4))) short short4v;
typedef __attribute__((ext_vector_type(4))) float f32x4;
typedef unsigned short ushort_t;

// fp32 -> bf16 bits, round-to-nearest-even
__device__ __forceinline__ unsigned short f2b(float x) {
    unsigned int u = __float_as_uint(x);
    u += 0x7FFFu + ((u >> 16) & 1u);
    return (unsigned short)(u >> 16);
}

// async global->LDS, 16B per lane; LDS dest = wave-uniform base + lane*16
#define ASYNC_COPY16(gp, lp) \
    __builtin_amdgcn_global_load_lds((const __attribute__((address_space(1))) void*)(gp), \
                                     (__attribute__((address_space(3))) void*)(lp), 16, 0, 0)

// ---------------------------------------------------------------------------
// Merged prep kernel: [0,1024) cast x; [1024,2560) transpose w_qkv;
// [2560,3072) transpose w_out.
// ---------------------------------------------------------------------------
__global__ __launch_bounds__(256)
void prep(const float* __restrict__ x, const float* __restrict__ w_qkv,
          const float* __restrict__ w_out, ushort_t* __restrict__ xb,
          ushort_t* __restrict__ wqb, ushort_t* __restrict__ wob)
{
    const int bid = blockIdx.x;
    if (bid < 1024) {
        constexpr int n4 = (BATCH * SEQ * DIM) / 4;
        int i = bid * 256 + threadIdx.x;
        for (; i < n4; i += 1024 * 256) {
            float4 v = ((const float4*)x)[i];
            short4v o;
            o[0] = (short)f2b(v.x); o[1] = (short)f2b(v.y);
            o[2] = (short)f2b(v.z); o[3] = (short)f2b(v.w);
            ((short4v*)xb)[i] = o;
        }
    } else {
        const int lane = threadIdx.x & 63;
        const float* src; ushort_t* dst; int N, job;
        if (bid < 2560) { src = w_qkv; dst = wqb; N = 3072; job = (bid - 1024) * 4 + (threadIdx.x >> 6); }
        else            { src = w_out; dst = wob; N = 1024; job = (bid - 2560) * 4 + (threadIdx.x >> 6); }
        const int jn = (N == 3072) ? (job % 48) : (job % 16);
        const int jk = (N == 3072) ? (job / 48) : (job / 16);
        const int n  = jn * 64 + lane;
        const int k0 = jk * 8;
        short8 o;
        #pragma unroll
        for (int j = 0; j < 8; ++j) o[j] = (short)f2b(src[(size_t)(k0 + j) * N + n]);
        *(short8*)(dst + (size_t)n * K_DIM + k0) = o;
    }
}

// ---------------------------------------------------------------------------
// 128x128 MFMA GEMM mainloop (R6 measured-best): BK=32, double-buffered LDS
// (8KB/buf/matrix), post-barrier prefetch, chunk-XOR swizzle.
// ---------------------------------------------------------------------------
__device__ __forceinline__ void gemm_stage(const ushort_t* __restrict__ Ag,
                                           const ushort_t* __restrict__ Bg,
                                           ushort_t* As, ushort_t* Bs,
                                           int k0, int w, int r0, int c0)
{
    ASYNC_COPY16(Ag + (size_t)r0 * K_DIM + k0 + c0 * 8,        As + w * 512);
    ASYNC_COPY16(Ag + (size_t)(64 + r0) * K_DIM + k0 + c0 * 8, As + w * 512 + 2048);
    ASYNC_COPY16(Bg + (size_t)r0 * K_DIM + k0 + c0 * 8,        Bs + w * 512);
    ASYNC_COPY16(Bg + (size_t)(64 + r0) * K_DIM + k0 + c0 * 8, Bs + w * 512 + 2048);
}

__device__ __forceinline__ void mfma_gemm_tile(
    const ushort_t* __restrict__ Ag, const ushort_t* __restrict__ Bg,
    ushort_t (&As)[2][128 * 32], ushort_t (&Bs)[2][128 * 32], f32x4 acc[4][4])
{
    const int t = threadIdx.x;
    const int w = t >> 6, lane = t & 63;
    const int qd = lane >> 4, cl = lane & 15;
    const int p0 = w * 64 + lane;
    const int r0 = p0 >> 2;
    const int c0 = (p0 & 3) ^ (r0 & 3);

    gemm_stage(Ag, Bg, As[0], Bs[0], 0, w, r0, c0);

    for (int kt = 0; kt < K_DIM / 32; ++kt) {
        const int cur = kt & 1;
        __syncthreads();
        if (kt + 1 < K_DIM / 32)
            gemm_stage(Ag, Bg, As[cur ^ 1], Bs[cur ^ 1], (kt + 1) * 32, w, r0, c0);

        short8 af[4], bfr[4];
        #pragma unroll
        for (int rt = 0; rt < 4; ++rt) {
            const int row = (w >> 1) * 64 + rt * 16 + cl;
            af[rt] = *(const short8*)(As[cur] + row * 32 + ((qd ^ (row & 3)) * 8));
        }
        #pragma unroll
        for (int ct = 0; ct < 4; ++ct) {
            const int col = (w & 1) * 64 + ct * 16 + cl;
            bfr[ct] = *(const short8*)(Bs[cur] + col * 32 + ((qd ^ (col & 3)) * 8));
        }
        #pragma unroll
        for (int rt = 0; rt < 4; ++rt)
            #pragma unroll
            for (int ct = 0; ct < 4; ++ct)
                acc[rt][ct] = __builtin_amdgcn_mfma_f32_16x16x32_bf16(
                    af[rt], bfr[ct], acc[rt][ct], 0, 0, 0);
    }
}

// ---------------------------------------------------------------------------
// GEMM1: qkv = xb @ wqb^T with fused RoPE + bf16 stores (d' = cl*4+ct perm).
// ---------------------------------------------------------------------------
__global__ __launch_bounds__(256, 3)
void gemm_qkv_mfma(const ushort_t* __restrict__ xb, const ushort_t* __restrict__ wqb,
                   ushort_t* __restrict__ qb, ushort_t* __restrict__ kb,
                   ushort_t* __restrict__ vt,
                   const float* __restrict__ cosb, const float* __restrict__ sinb)
{
    __shared__ __align__(16) ushort_t As[2][128 * 32];
    __shared__ __align__(16) ushort_t Bs[2][128 * 32];
    const int m0 = blockIdx.y * 128, n0 = blockIdx.x * 128;

    f32x4 acc[4][4];
    #pragma unroll
    for (int i = 0; i < 4; ++i)
        #pragma unroll
        for (int j = 0; j < 4; ++j)
            #pragma unroll
            for (int r = 0; r < 4; ++r) acc[i][j][r] = 0.f;

    mfma_gemm_tile(xb + (size_t)m0 * K_DIM, wqb + (size_t)n0 * K_DIM, As, Bs, acc);

    const int t = threadIdx.x, w = t >> 6, lane = t & 63;
    const int qd = lane >> 4, cl = lane & 15;
    const int b = m0 >> 11;
    const int lbase = (m0 & 2047) + (w >> 1) * 64;
    const int region = blockIdx.x >> 3;              // 0=q, 1=k, 2=v
    const int h = (blockIdx.x & 7) * 2 + (w & 1);

    if (region < 2) {
        ushort_t* dst = region ? kb : qb;
        const float sc = region ? 1.0f : 0.18033688011111234f;  // 0.125*log2(e)
        #pragma unroll
        for (int rt = 0; rt < 4; ++rt) {
            #pragma unroll
            for (int r = 0; r < 4; ++r) {
                const int l = lbase + rt * 16 + qd * 4 + r;
                const float c0 = cosb[l * HD + cl],      s0 = sinb[l * HD + cl];
                const float c1 = cosb[l * HD + 16 + cl], s1 = sinb[l * HD + 16 + cl];
                const float v0 = acc[rt][0][r] * c0 - acc[rt][2][r] * s0;
                const float v1 = acc[rt][1][r] * c1 - acc[rt][3][r] * s1;
                const float v2 = acc[rt][2][r] * c0 + acc[rt][0][r] * s0;
                const float v3 = acc[rt][3][r] * c1 + acc[rt][1][r] * s1;
                short4v o4;
                o4[0] = (short)f2b(v0 * sc);
                o4[1] = (short)f2b(v1 * sc);
                o4[2] = (short)f2b(v2 * sc);
                o4[3] = (short)f2b(v3 * sc);
                *(short4v*)(dst + (((size_t)b * NH + h) * SEQ + l) * HD + cl * 4) = o4;
            }
        }
    } else {
        #pragma unroll
        for (int rt = 0; rt < 4; ++rt)
            #pragma unroll
            for (int ct = 0; ct < 4; ++ct) {
                const int d = ct * 16 + cl;
                const int l = lbase + rt * 16 + qd * 4;
                short4v o4;
                #pragma unroll
                for (int r = 0; r < 4; ++r) o4[r] = (short)f2b(acc[rt][ct][r]);
                *(short4v*)(vt + (((size_t)b * NH + h) * HD + d) * SEQ + l) = o4;
            }
    }
}

// ---------------------------------------------------------------------------
// GEMM2: out = ob @ wob^T, 128x64 tiles (512 blocks -> 2 blocks/CU), BK=32
// dbuf staging, fp32 store.
// ---------------------------------------------------------------------------
__device__ __forceinline__ void go_stage(const ushort_t* __restrict__ Ag,
                                         const ushort_t* __restrict__ Bg,
                                         ushort_t* As, ushort_t* Bs,
                                         int k0, int w, int lane)
{
    #pragma unroll
    for (int j = 0; j < 2; ++j) {
        const int r = w * 32 + j * 16 + (lane >> 2);
        const int c = (lane & 3) ^ (r & 3);
        ASYNC_COPY16(Ag + (size_t)r * K_DIM + k0 + c * 8, As + (w * 128 + j * 64) * 8);
    }
    const int rb = w * 16 + (lane >> 2);
    const int cb = (lane & 3) ^ (rb & 3);
    ASYNC_COPY16(Bg + (size_t)rb * K_DIM + k0 + cb * 8, Bs + (w * 64) * 8);
}

__global__ __launch_bounds__(256, 3)
void gemm_out_mfma(const ushort_t* __restrict__ ob, const ushort_t* __restrict__ wob,
                   float* __restrict__ out)
{
    __shared__ __align__(16) ushort_t As[2][128 * 32];
    __shared__ __align__(16) ushort_t Bs[2][64 * 32];
    const int m0 = blockIdx.y * 128, n0 = blockIdx.x * 64;
    const int t = threadIdx.x;
    const int w = t >> 6, lane = t & 63;
    const int qd = lane >> 4, cl = lane & 15;
    const int wr = w >> 1, wc = w & 1;

    f32x4 acc[4][2];
    #pragma unroll
    for (int i = 0; i < 4; ++i)
        #pragma unroll
        for (int j = 0; j < 2; ++j)
            #pragma unroll
            for (int r = 0; r < 4; ++r) acc[i][j][r] = 0.f;

    const ushort_t* Ag = ob  + (size_t)m0 * K_DIM;
    const ushort_t* Bg = wob + (size_t)n0 * K_DIM;
    go_stage(Ag, Bg, As[0], Bs[0], 0, w, lane);

    for (int kt = 0; kt < K_DIM / 32; ++kt) {
        const int cur = kt & 1;
        __syncthreads();
        if (kt + 1 < K_DIM / 32)
            go_stage(Ag, Bg, As[cur ^ 1], Bs[cur ^ 1], (kt + 1) * 32, w, lane);

        short8 af[4], bfr[2];
        #pragma unroll
        for (int rt = 0; rt < 4; ++rt) {
            const int row = wr * 64 + rt * 16 + cl;
            af[rt] = *(const short8*)(As[cur] + row * 32 + ((qd ^ (row & 3)) * 8));
        }
        #pragma unroll
        for (int ct = 0; ct < 2; ++ct) {
            const int col = wc * 32 + ct * 16 + cl;
            bfr[ct] = *(const short8*)(Bs[cur] + col * 32 + ((qd ^ (col & 3)) * 8));
        }
        #pragma unroll
        for (int rt = 0; rt < 4; ++rt)
            #pragma unroll
            for (int ct = 0; ct < 2; ++ct)
                acc[rt][ct] = __builtin_amdgcn_mfma_f32_16x16x32_bf16(
                    af[rt], bfr[ct], acc[rt][ct], 0, 0, 0);
    }

    const int mbase = m0 + wr * 64, nbase = n0 + wc * 32;
    #pragma unroll
    for (int rt = 0; rt < 4; ++rt)
        #pragma unroll
        for (int ct = 0; ct < 2; ++ct)
            #pragma unroll
            for (int r = 0; r < 4; ++r)
                out[(size_t)(mbase + rt * 16 + qd * 4 + r) * DIM + nbase + ct * 16 + cl] =
                    acc[rt][ct][r];
}

// ---------------------------------------------------------------------------
// Flash attention v10: v9 + tile-loop unrolled x2 with STATIC buffer/register
// sets. Removes per-iter VALU overhead: LDS read addresses hoisted (8 base
// addrs, ds_read offset: immediates), PV-deferral via alternating pfE/vfE <->
// pfO/vfO register sets (no copies), S init folded into first MFMA (C=zero4),
// l computed by MFMA with all-ones A-fragment (kills the 24-add serial chain
// and the epilogue shuffles; l is exactly consistent with bf16 P). Sync
// structure unchanged from v9 (proven): __syncthreads + post-barrier
// prefetch, 2-buffer. LDS 32KB, grid 512 = 2 blocks/CU, launch_bounds(256,2).
// ---------------------------------------------------------------------------
__global__ __launch_bounds__(256, 2)
void attn_mfma(const ushort_t* __restrict__ qb, const ushort_t* __restrict__ kb,
               const ushort_t* __restrict__ vt, ushort_t* __restrict__ ob)
{
    const int h = blockIdx.x;                 // fastest -> K/V sharers on one XCD
    const int b = blockIdx.y;
    const int qt = blockIdx.z;                // 0..15, 128 queries per block
    const int t = threadIdx.x;
    const int w = t >> 6, lane = t & 63;
    const int qd = lane >> 4, cl = lane & 15;
    constexpr int NT = SEQ / 64;              // 32 tiles, full range

    __shared__ __align__(16) ushort_t Ks[2][64 * 64];
    __shared__ __align__(16) ushort_t Vs[2][64 * 64];

    const size_t bh = (size_t)b * NH + h;
    const ushort_t* qbase = qb + (bh * SEQ + qt * 128 + w * 32) * HD;
    const ushort_t* kbase = kb + bh * SEQ * HD;
    const ushort_t* vbase = vt + bh * (size_t)HD * SEQ;

    const int p0 = w * 128 + lane;
    const int r0a = p0 >> 3,  c0a = (p0 & 7) ^ (r0a & 7);
    const int p1 = p0 + 64;
    const int r1a = p1 >> 3,  c1a = (p1 & 7) ^ (r1a & 7);
    const int ldsoff0 = (w * 128) * 8;
    const int ldsoff1 = (w * 128 + 64) * 8;

    // staging pointers, advanced one 64-tile per stage
    const ushort_t* kg0 = kbase + (size_t)r0a * HD + c0a * 8;
    const ushort_t* kg1 = kbase + (size_t)r1a * HD + c1a * 8;
    const ushort_t* vg0 = vbase + (size_t)r0a * SEQ + c0a * 8;
    const ushort_t* vg1 = vbase + (size_t)r1a * SEQ + c1a * 8;

    // hoisted LDS read base addresses (per buffer, per kh); reads use
    // immediate offsets mt*2048 bytes off these.
    const int lo0 = (cl * 8 + (qd ^ (cl & 7))) * 8;
    const int lo1 = (cl * 8 + ((4 + qd) ^ (cl & 7))) * 8;
    const ushort_t* kE0 = Ks[0] + lo0; const ushort_t* kE1 = Ks[0] + lo1;
    const ushort_t* vE0 = Vs[0] + lo0; const ushort_t* vE1 = Vs[0] + lo1;
    const ushort_t* kO0 = Ks[1] + lo0; const ushort_t* kO1 = Ks[1] + lo1;
    const ushort_t* vO0 = Vs[1] + lo0; const ushort_t* vO1 = Vs[1] + lo1;

    short8 qf[2][2];
    #pragma unroll
    for (int nt = 0; nt < 2; ++nt)
        #pragma unroll
        for (int kh = 0; kh < 2; ++kh)
            qf[nt][kh] = *(const short8*)(qbase + (nt * 16 + cl) * HD + kh * 32 + qd * 8);

    const f32x4 fz = {0.f, 0.f, 0.f, 0.f};
    short8 onesA;
    #pragma unroll
    for (int e = 0; e < 8; ++e) onesA[e] = (short)0x3F80;   // bf16 1.0

    f32x4 oaccT[4][2];
    f32x4 lacc[2];
    #pragma unroll
    for (int dt = 0; dt < 4; ++dt)
        #pragma unroll
        for (int nt = 0; nt < 2; ++nt)
            #pragma unroll
            for (int r = 0; r < 4; ++r) oaccT[dt][nt][r] = 0.f;
    #pragma unroll
    for (int nt = 0; nt < 2; ++nt)
        #pragma unroll
        for (int r = 0; r < 4; ++r) lacc[nt][r] = 0.f;

    // alternating deferred-PV register sets; odd set zeroed (first even-body
    // PV is then a no-op)
    short8 pfE[2][2], vfE[4][2], pfO[2][2], vfO[4][2];
    #pragma unroll
    for (int nt = 0; nt < 2; ++nt)
        #pragma unroll
        for (int kh = 0; kh < 2; ++kh)
            #pragma unroll
            for (int e = 0; e < 8; ++e) pfO[nt][kh][e] = 0;
    #pragma unroll
    for (int dt = 0; dt < 4; ++dt)
        #pragma unroll
        for (int kh = 0; kh < 2; ++kh)
            #pragma unroll
            for (int e = 0; e < 8; ++e) vfO[dt][kh][e] = 0;

    {   // stage tile 0 into buffer 0
        ASYNC_COPY16(kg0, (ushort_t*)Ks[0] + ldsoff0);
        ASYNC_COPY16(kg1, (ushort_t*)Ks[0] + ldsoff1);
        ASYNC_COPY16(vg0, (ushort_t*)Vs[0] + ldsoff0);
        ASYNC_COPY16(vg1, (ushort_t*)Vs[0] + ldsoff1);
        kg0 += 64 * HD; kg1 += 64 * HD; vg0 += 64; vg1 += 64;
    }

    for (int pr = 0; pr < NT / 2; ++pr) {
        // ================= even tile (2*pr) in buffer 0 =================
        __syncthreads();
        {   // stage odd tile (2*pr+1) -> buffer 1 (always in range, NT even)
            ASYNC_COPY16(kg0, (ushort_t*)Ks[1] + ldsoff0);
            ASYNC_COPY16(kg1, (ushort_t*)Ks[1] + ldsoff1);
            ASYNC_COPY16(vg0, (ushort_t*)Vs[1] + ldsoff0);
            ASYNC_COPY16(vg1, (ushort_t*)Vs[1] + ldsoff1);
            kg0 += 64 * HD; kg1 += 64 * HD; vg0 += 64; vg1 += 64;
        }
        {
            short8 kf[4][2];
            #pragma unroll
            for (int mt = 0; mt < 4; ++mt) {
                kf[mt][0] = *(const short8*)(kE0 + mt * 1024);
                kf[mt][1] = *(const short8*)(kE1 + mt * 1024);
            }
            #pragma unroll
            for (int dt = 0; dt < 4; ++dt) {
                vfE[dt][0] = *(const short8*)(vE0 + dt * 1024);
                vfE[dt][1] = *(const short8*)(vE1 + dt * 1024);
            }
            f32x4 s[4][2];
            __builtin_amdgcn_s_setprio(1);
            #pragma unroll
            for (int mt = 0; mt < 4; ++mt)
                #pragma unroll
                for (int nt = 0; nt < 2; ++nt)
                    s[mt][nt] = __builtin_amdgcn_mfma_f32_16x16x32_bf16(
                        kf[mt][0], qf[nt][0], fz, 0, 0, 0);
            #pragma unroll
            for (int mt = 0; mt < 4; ++mt)
                #pragma unroll
                for (int nt = 0; nt < 2; ++nt)
                    s[mt][nt] = __builtin_amdgcn_mfma_f32_16x16x32_bf16(
                        kf[mt][1], qf[nt][1], s[mt][nt], 0, 0, 0);
            // deferred PV of odd tile (2*pr-1)
            #pragma unroll
            for (int kh = 0; kh < 2; ++kh)
                #pragma unroll
                for (int dt = 0; dt < 4; ++dt)
                    #pragma unroll
                    for (int nt = 0; nt < 2; ++nt)
                        oaccT[dt][nt] = __builtin_amdgcn_mfma_f32_16x16x32_bf16(
                            vfO[dt][kh], pfO[nt][kh], oaccT[dt][nt], 0, 0, 0);
            __builtin_amdgcn_s_setprio(0);
            // exp2 + pack + in-register redistribution -> pfE
            #pragma unroll
            for (int nt = 0; nt < 2; ++nt) {
                unsigned int wr2[4][2];
                #pragma unroll
                for (int mt = 0; mt < 4; ++mt) {
                    const float e0 = __builtin_amdgcn_exp2f(s[mt][nt][0]);
                    const float e1 = __builtin_amdgcn_exp2f(s[mt][nt][1]);
                    const float e2 = __builtin_amdgcn_exp2f(s[mt][nt][2]);
                    const float e3 = __builtin_amdgcn_exp2f(s[mt][nt][3]);
                    union { __hip_bfloat162 h2; unsigned int u; } pk0, pk1;
                    pk0.h2 = __float22bfloat162_rn(make_float2(e0, e1));
                    pk1.h2 = __float22bfloat162_rn(make_float2(e2, e3));
                    wr2[mt][0] = pk0.u;
                    wr2[mt][1] = pk1.u;
                }
                #pragma unroll
                for (int kh = 0; kh < 2; ++kh) {
                    union { unsigned int u[4]; short8 s8; } pu;
                    #pragma unroll
                    for (int i = 0; i < 2; ++i) {
                        unsigned int a  = wr2[2 * kh][i];
                        unsigned int bb = wr2[2 * kh + 1][i];
                        asm("v_permlane32_swap_b32 %0, %1" : "+v"(a), "+v"(bb));
                        asm("v_permlane16_swap_b32 %0, %1" : "+v"(a), "+v"(bb));
                        pu.u[i]     = a;
                        pu.u[2 + i] = bb;
                    }
                    pfE[nt][kh] = pu.s8;
                }
            }
            // l accumulation on the matrix pipe (rows of D all equal l[q])
            #pragma unroll
            for (int kh = 0; kh < 2; ++kh)
                #pragma unroll
                for (int nt = 0; nt < 2; ++nt)
                    lacc[nt] = __builtin_amdgcn_mfma_f32_16x16x32_bf16(
                        onesA, pfE[nt][kh], lacc[nt], 0, 0, 0);
        }

        // ================= odd tile (2*pr+1) in buffer 1 =================
        __syncthreads();
        if (pr + 1 < NT / 2) {   // stage even tile (2*pr+2) -> buffer 0
            ASYNC_COPY16(kg0, (ushort_t*)Ks[0] + ldsoff0);
            ASYNC_COPY16(kg1, (ushort_t*)Ks[0] + ldsoff1);
            ASYNC_COPY16(vg0, (ushort_t*)Vs[0] + ldsoff0);
            ASYNC_COPY16(vg1, (ushort_t*)Vs[0] + ldsoff1);
            kg0 += 64 * HD; kg1 += 64 * HD; vg0 += 64; vg1 += 64;
        }
        {
            short8 kf[4][2];
            #pragma unroll
            for (int mt = 0; mt < 4; ++mt) {
                kf[mt][0] = *(const short8*)(kO0 + mt * 1024);
                kf[mt][1] = *(const short8*)(kO1 + mt * 1024);
            }
            #pragma unroll
            for (int dt = 0; dt < 4; ++dt) {
                vfO[dt][0] = *(const short8*)(vO0 + dt * 1024);
                vfO[dt][1] = *(const short8*)(vO1 + dt * 1024);
            }
            f32x4 s[4][2];
            __builtin_amdgcn_s_setprio(1);
            #pragma unroll
            for (int mt = 0; mt < 4; ++mt)
                #pragma unroll
                for (int nt = 0; nt < 2; ++nt)
                    s[mt][nt] = __builtin_amdgcn_mfma_f32_16x16x32_bf16(
                        kf[mt][0], qf[nt][0], fz, 0, 0, 0);
            #pragma unroll
            for (int mt = 0; mt < 4; ++mt)
                #pragma unroll
                for (int nt = 0; nt < 2; ++nt)
                    s[mt][nt] = __builtin_amdgcn_mfma_f32_16x16x32_bf16(
                        kf[mt][1], qf[nt][1], s[mt][nt], 0, 0, 0);
            // deferred PV of even tile (2*pr)
            #pragma unroll
            for (int kh = 0; kh < 2; ++kh)
                #pragma unroll
                for (int dt = 0; dt < 4; ++dt)
                    #pragma unroll
                    for (int nt = 0; nt < 2; ++nt)
                        oaccT[dt][nt] = __builtin_amdgcn_mfma_f32_16x16x32_bf16(
                            vfE[dt][kh], pfE[nt][kh], oaccT[dt][nt], 0, 0, 0);
            __builtin_amdgcn_s_setprio(0);
            // exp2 + pack + in-register redistribution -> pfO
            #pragma unroll
            for (int nt = 0; nt < 2; ++nt) {
                unsigned int wr2[4][2];
                #pragma unroll
                for (int mt = 0; mt < 4; ++mt) {
                    const float e0 = __builtin_amdgcn_exp2f(s[mt][nt][0]);
                    const float e1 = __builtin_amdgcn_exp2f(s[mt][nt][1]);
                    const float e2 = __builtin_amdgcn_exp2f(s[mt][nt][2]);
                    const float e3 = __builtin_amdgcn_exp2f(s[mt][nt][3]);
                    union { __hip_bfloat162 h2; unsigned int u; } pk0, pk1;
                    pk0.h2 = __float22bfloat162_rn(make_float2(e0, e1));
                    pk1.h2 = __float22bfloat162_rn(make_float2(e2, e3));
                    wr2[mt][0] = pk0.u;
                    wr2[mt][1] = pk1.u;
                }
                #pragma unroll
                for (int kh = 0; kh < 2; ++kh) {
                    union { unsigned int u[4]; short8 s8; } pu;
                    #pragma unroll
                    for (int i = 0; i < 2; ++i) {
                        unsigned int a  = wr2[2 * kh][i];
                        unsigned int bb = wr2[2 * kh + 1][i];
                        asm("v_permlane32_swap_b32 %0, %1" : "+v"(a), "+v"(bb));
                        asm("v_permlane16_swap_b32 %0, %1" : "+v"(a), "+v"(bb));
                        pu.u[i]     = a;
                        pu.u[2 + i] = bb;
                    }
                    pfO[nt][kh] = pu.s8;
                }
            }
            #pragma unroll
            for (int kh = 0; kh < 2; ++kh)
                #pragma unroll
                for (int nt = 0; nt < 2; ++nt)
                    lacc[nt] = __builtin_amdgcn_mfma_f32_16x16x32_bf16(
                        onesA, pfO[nt][kh], lacc[nt], 0, 0, 0);
        }
    }

    // tail PV for the last (odd) tile
    #pragma unroll
    for (int kh = 0; kh < 2; ++kh)
        #pragma unroll
        for (int dt = 0; dt < 4; ++dt)
            #pragma unroll
            for (int nt = 0; nt < 2; ++nt)
                oaccT[dt][nt] = __builtin_amdgcn_mfma_f32_16x16x32_bf16(
                    vfO[dt][kh], pfO[nt][kh], oaccT[dt][nt], 0, 0, 0);

    // ---- epilogue: l comes straight from lacc (all rows equal) ----
    #pragma unroll
    for (int nt = 0; nt < 2; ++nt) {
        const float inv = 1.0f / lacc[nt][0];
        const int query = qt * 128 + w * 32 + nt * 16 + cl;
        ushort_t* op = ob + ((size_t)b * SEQ + query) * DIM + h * HD;
        #pragma unroll
        for (int dt = 0; dt < 4; ++dt) {
            short4v o4;
            #pragma unroll
            for (int r = 0; r < 4; ++r) o4[r] = (short)f2b(oaccT[dt][nt][r] * inv);
            *(short4v*)(op + dt * 16 + qd * 4) = o4;
        }
    }
}

// ---------------------------------------------------------------------------
extern "C" void kernel_launch(void* const* d_in, const int* in_sizes, int n_in,
                              void* d_out, int out_size, void* d_ws, size_t ws_size,
                              hipStream_t stream)
{
    const float* x     = (const float*)d_in[0];
    const float* cosb  = (const float*)d_in[1];
    const float* sinb  = (const float*)d_in[2];
    const float* w_qkv = (const float*)d_in[3];
    const float* w_out = (const float*)d_in[4];
    float* out = (float*)d_out;

    // workspace layout (peak 48MB, no aliasing hazards):
    //  [0,8)   qb   [8,16) kb   [16,24) vt   [24,26) wob
    //  [26,34) ob   [34,42) xb  [42,48) wqb
    constexpr size_t MB = 1u << 20;
    char* ws = (char*)d_ws;
    ushort_t* qb  = (ushort_t*)(ws);
    ushort_t* kb  = (ushort_t*)(ws + 8 * MB);
    ushort_t* vt  = (ushort_t*)(ws + 16 * MB);
    ushort_t* wob = (ushort_t*)(ws + 24 * MB);
    ushort_t* ob  = (ushort_t*)(ws + 26 * MB);
    ushort_t* xb  = (ushort_t*)(ws + 34 * MB);
    ushort_t* wqb = (ushort_t*)(ws + 42 * MB);

    prep<<<3072, 256, 0, stream>>>(x, w_qkv, w_out, xb, wqb, wob);
    gemm_qkv_mfma<<<dim3(24, 32), 256, 0, stream>>>(xb, wqb, qb, kb, vt, cosb, sinb);
    attn_mfma<<<dim3(16, 2, 16), 256, 0, stream>>>(qb, kb, vt, ob);
    gemm_out_mfma<<<dim3(16, 32), 256, 0, stream>>>(ob, wob, out);
}

// Round 4
// 190.764 us; speedup vs baseline: 1.0812x; 1.0010x over previous
//
#include <hip/hip_runtime.h>
#include <hip/hip_bf16.h>

#define BATCH 2
#define SEQ   2048
#define DIM   1024
#define NH    16
#define HD    64
#define K_DIM 1024

typedef __attribute__((ext_vector_type(8))) short short8;
typedef __attribute__((ext_vector_type(4))) short short4v;
typedef __attribute__((ext_vector_type(4))) float f32x4;
typedef unsigned short ushort_t;

// fp32 -> bf16 bits, round-to-nearest-even
__device__ __forceinline__ unsigned short f2b(float x) {
    unsigned int u = __float_as_uint(x);
    u += 0x7FFFu + ((u >> 16) & 1u);
    return (unsigned short)(u >> 16);
}

// async global->LDS, 16B per lane; LDS dest = wave-uniform base + lane*16
#define ASYNC_COPY16(gp, lp) \
    __builtin_amdgcn_global_load_lds((const __attribute__((address_space(1))) void*)(gp), \
                                     (__attribute__((address_space(3))) void*)(lp), 16, 0, 0)

// ---------------------------------------------------------------------------
// Merged prep kernel: [0,1024) cast x; [1024,2560) transpose w_qkv;
// [2560,3072) transpose w_out.
// ---------------------------------------------------------------------------
__global__ __launch_bounds__(256)
void prep(const float* __restrict__ x, const float* __restrict__ w_qkv,
          const float* __restrict__ w_out, ushort_t* __restrict__ xb,
          ushort_t* __restrict__ wqb, ushort_t* __restrict__ wob)
{
    const int bid = blockIdx.x;
    if (bid < 1024) {
        constexpr int n4 = (BATCH * SEQ * DIM) / 4;
        int i = bid * 256 + threadIdx.x;
        for (; i < n4; i += 1024 * 256) {
            float4 v = ((const float4*)x)[i];
            short4v o;
            o[0] = (short)f2b(v.x); o[1] = (short)f2b(v.y);
            o[2] = (short)f2b(v.z); o[3] = (short)f2b(v.w);
            ((short4v*)xb)[i] = o;
        }
    } else {
        const int lane = threadIdx.x & 63;
        const float* src; ushort_t* dst; int N, job;
        if (bid < 2560) { src = w_qkv; dst = wqb; N = 3072; job = (bid - 1024) * 4 + (threadIdx.x >> 6); }
        else            { src = w_out; dst = wob; N = 1024; job = (bid - 2560) * 4 + (threadIdx.x >> 6); }
        const int jn = (N == 3072) ? (job % 48) : (job % 16);
        const int jk = (N == 3072) ? (job / 48) : (job / 16);
        const int n  = jn * 64 + lane;
        const int k0 = jk * 8;
        short8 o;
        #pragma unroll
        for (int j = 0; j < 8; ++j) o[j] = (short)f2b(src[(size_t)(k0 + j) * N + n]);
        *(short8*)(dst + (size_t)n * K_DIM + k0) = o;
    }
}

// ---------------------------------------------------------------------------
// 128x128 MFMA GEMM mainloop: BK=32, double-buffered LDS, post-barrier
// prefetch, chunk-XOR swizzle. R9: k-loop unrolled x2 with STATIC buffer
// addressing (hoisted LDS base pointers, buf1 via +8192B immediate).
// ---------------------------------------------------------------------------
__device__ __forceinline__ void gemm_stage(const ushort_t* __restrict__ Ag,
                                           const ushort_t* __restrict__ Bg,
                                           ushort_t* As, ushort_t* Bs,
                                           int k0, int w, int r0, int c0)
{
    ASYNC_COPY16(Ag + (size_t)r0 * K_DIM + k0 + c0 * 8,        As + w * 512);
    ASYNC_COPY16(Ag + (size_t)(64 + r0) * K_DIM + k0 + c0 * 8, As + w * 512 + 2048);
    ASYNC_COPY16(Bg + (size_t)r0 * K_DIM + k0 + c0 * 8,        Bs + w * 512);
    ASYNC_COPY16(Bg + (size_t)(64 + r0) * K_DIM + k0 + c0 * 8, Bs + w * 512 + 2048);
}

__device__ __forceinline__ void mfma_gemm_tile(
    const ushort_t* __restrict__ Ag, const ushort_t* __restrict__ Bg,
    ushort_t (&As)[2][128 * 32], ushort_t (&Bs)[2][128 * 32], f32x4 acc[4][4])
{
    const int t = threadIdx.x;
    const int w = t >> 6, lane = t & 63;
    const int qd = lane >> 4, cl = lane & 15;
    const int p0 = w * 64 + lane;
    const int r0 = p0 >> 2;
    const int c0 = (p0 & 3) ^ (r0 & 3);

    // hoisted LDS read bases (buffer 0; buffer 1 = +4096 ushorts = 8192B imm)
    const ushort_t* aB[4];
    const ushort_t* bB[4];
    #pragma unroll
    for (int rt = 0; rt < 4; ++rt) {
        const int row = (w >> 1) * 64 + rt * 16 + cl;
        aB[rt] = As[0] + row * 32 + ((qd ^ (row & 3)) * 8);
    }
    #pragma unroll
    for (int ct = 0; ct < 4; ++ct) {
        const int col = (w & 1) * 64 + ct * 16 + cl;
        bB[ct] = Bs[0] + col * 32 + ((qd ^ (col & 3)) * 8);
    }

    gemm_stage(Ag, Bg, As[0], Bs[0], 0, w, r0, c0);

    for (int kp = 0; kp < K_DIM / 64; ++kp) {
        // ---- even step (buffer 0), k = kp*64 ----
        __syncthreads();
        gemm_stage(Ag, Bg, As[1], Bs[1], kp * 64 + 32, w, r0, c0);
        {
            short8 af[4], bfr[4];
            #pragma unroll
            for (int rt = 0; rt < 4; ++rt) af[rt] = *(const short8*)(aB[rt]);
            #pragma unroll
            for (int ct = 0; ct < 4; ++ct) bfr[ct] = *(const short8*)(bB[ct]);
            #pragma unroll
            for (int rt = 0; rt < 4; ++rt)
                #pragma unroll
                for (int ct = 0; ct < 4; ++ct)
                    acc[rt][ct] = __builtin_amdgcn_mfma_f32_16x16x32_bf16(
                        af[rt], bfr[ct], acc[rt][ct], 0, 0, 0);
        }
        // ---- odd step (buffer 1), k = kp*64+32 ----
        __syncthreads();
        if (kp + 1 < K_DIM / 64)
            gemm_stage(Ag, Bg, As[0], Bs[0], kp * 64 + 64, w, r0, c0);
        {
            short8 af[4], bfr[4];
            #pragma unroll
            for (int rt = 0; rt < 4; ++rt) af[rt] = *(const short8*)(aB[rt] + 4096);
            #pragma unroll
            for (int ct = 0; ct < 4; ++ct) bfr[ct] = *(const short8*)(bB[ct] + 4096);
            #pragma unroll
            for (int rt = 0; rt < 4; ++rt)
                #pragma unroll
                for (int ct = 0; ct < 4; ++ct)
                    acc[rt][ct] = __builtin_amdgcn_mfma_f32_16x16x32_bf16(
                        af[rt], bfr[ct], acc[rt][ct], 0, 0, 0);
        }
    }
}

// ---------------------------------------------------------------------------
// GEMM1: qkv = xb @ wqb^T with fused RoPE + bf16 stores (d' = cl*4+ct perm).
// ---------------------------------------------------------------------------
__global__ __launch_bounds__(256, 3)
void gemm_qkv_mfma(const ushort_t* __restrict__ xb, const ushort_t* __restrict__ wqb,
                   ushort_t* __restrict__ qb, ushort_t* __restrict__ kb,
                   ushort_t* __restrict__ vt,
                   const float* __restrict__ cosb, const float* __restrict__ sinb)
{
    __shared__ __align__(16) ushort_t As[2][128 * 32];
    __shared__ __align__(16) ushort_t Bs[2][128 * 32];
    const int m0 = blockIdx.y * 128, n0 = blockIdx.x * 128;

    f32x4 acc[4][4];
    #pragma unroll
    for (int i = 0; i < 4; ++i)
        #pragma unroll
        for (int j = 0; j < 4; ++j)
            #pragma unroll
            for (int r = 0; r < 4; ++r) acc[i][j][r] = 0.f;

    mfma_gemm_tile(xb + (size_t)m0 * K_DIM, wqb + (size_t)n0 * K_DIM, As, Bs, acc);

    const int t = threadIdx.x, w = t >> 6, lane = t & 63;
    const int qd = lane >> 4, cl = lane & 15;
    const int b = m0 >> 11;
    const int lbase = (m0 & 2047) + (w >> 1) * 64;
    const int region = blockIdx.x >> 3;              // 0=q, 1=k, 2=v
    const int h = (blockIdx.x & 7) * 2 + (w & 1);

    if (region < 2) {
        ushort_t* dst = region ? kb : qb;
        const float sc = region ? 1.0f : 0.18033688011111234f;  // 0.125*log2(e)
        #pragma unroll
        for (int rt = 0; rt < 4; ++rt) {
            #pragma unroll
            for (int r = 0; r < 4; ++r) {
                const int l = lbase + rt * 16 + qd * 4 + r;
                const float c0 = cosb[l * HD + cl],      s0 = sinb[l * HD + cl];
                const float c1 = cosb[l * HD + 16 + cl], s1 = sinb[l * HD + 16 + cl];
                const float v0 = acc[rt][0][r] * c0 - acc[rt][2][r] * s0;
                const float v1 = acc[rt][1][r] * c1 - acc[rt][3][r] * s1;
                const float v2 = acc[rt][2][r] * c0 + acc[rt][0][r] * s0;
                const float v3 = acc[rt][3][r] * c1 + acc[rt][1][r] * s1;
                short4v o4;
                o4[0] = (short)f2b(v0 * sc);
                o4[1] = (short)f2b(v1 * sc);
                o4[2] = (short)f2b(v2 * sc);
                o4[3] = (short)f2b(v3 * sc);
                *(short4v*)(dst + (((size_t)b * NH + h) * SEQ + l) * HD + cl * 4) = o4;
            }
        }
    } else {
        #pragma unroll
        for (int rt = 0; rt < 4; ++rt)
            #pragma unroll
            for (int ct = 0; ct < 4; ++ct) {
                const int d = ct * 16 + cl;
                const int l = lbase + rt * 16 + qd * 4;
                short4v o4;
                #pragma unroll
                for (int r = 0; r < 4; ++r) o4[r] = (short)f2b(acc[rt][ct][r]);
                *(short4v*)(vt + (((size_t)b * NH + h) * HD + d) * SEQ + l) = o4;
            }
    }
}

// ---------------------------------------------------------------------------
// GEMM2: out = ob @ wob^T, 128x64 tiles (512 blocks -> 2 blocks/CU), BK=32
// dbuf staging, fp32 store. R9: x2 unroll, static buffers.
// ---------------------------------------------------------------------------
__device__ __forceinline__ void go_stage(const ushort_t* __restrict__ Ag,
                                         const ushort_t* __restrict__ Bg,
                                         ushort_t* As, ushort_t* Bs,
                                         int k0, int w, int lane)
{
    #pragma unroll
    for (int j = 0; j < 2; ++j) {
        const int r = w * 32 + j * 16 + (lane >> 2);
        const int c = (lane & 3) ^ (r & 3);
        ASYNC_COPY16(Ag + (size_t)r * K_DIM + k0 + c * 8, As + (w * 128 + j * 64) * 8);
    }
    const int rb = w * 16 + (lane >> 2);
    const int cb = (lane & 3) ^ (rb & 3);
    ASYNC_COPY16(Bg + (size_t)rb * K_DIM + k0 + cb * 8, Bs + (w * 64) * 8);
}

__global__ __launch_bounds__(256, 3)
void gemm_out_mfma(const ushort_t* __restrict__ ob, const ushort_t* __restrict__ wob,
                   float* __restrict__ out)
{
    __shared__ __align__(16) ushort_t As[2][128 * 32];
    __shared__ __align__(16) ushort_t Bs[2][64 * 32];
    const int m0 = blockIdx.y * 128, n0 = blockIdx.x * 64;
    const int t = threadIdx.x;
    const int w = t >> 6, lane = t & 63;
    const int qd = lane >> 4, cl = lane & 15;
    const int wr = w >> 1, wc = w & 1;

    f32x4 acc[4][2];
    #pragma unroll
    for (int i = 0; i < 4; ++i)
        #pragma unroll
        for (int j = 0; j < 2; ++j)
            #pragma unroll
            for (int r = 0; r < 4; ++r) acc[i][j][r] = 0.f;

    const ushort_t* Ag = ob  + (size_t)m0 * K_DIM;
    const ushort_t* Bg = wob + (size_t)n0 * K_DIM;

    const ushort_t* aB[4];
    const ushort_t* bB[2];
    #pragma unroll
    for (int rt = 0; rt < 4; ++rt) {
        const int row = wr * 64 + rt * 16 + cl;
        aB[rt] = As[0] + row * 32 + ((qd ^ (row & 3)) * 8);
    }
    #pragma unroll
    for (int ct = 0; ct < 2; ++ct) {
        const int col = wc * 32 + ct * 16 + cl;
        bB[ct] = Bs[0] + col * 32 + ((qd ^ (col & 3)) * 8);
    }

    go_stage(Ag, Bg, As[0], Bs[0], 0, w, lane);

    for (int kp = 0; kp < K_DIM / 64; ++kp) {
        __syncthreads();
        go_stage(Ag, Bg, As[1], Bs[1], kp * 64 + 32, w, lane);
        {
            short8 af[4], bfr[2];
            #pragma unroll
            for (int rt = 0; rt < 4; ++rt) af[rt] = *(const short8*)(aB[rt]);
            #pragma unroll
            for (int ct = 0; ct < 2; ++ct) bfr[ct] = *(const short8*)(bB[ct]);
            #pragma unroll
            for (int rt = 0; rt < 4; ++rt)
                #pragma unroll
                for (int ct = 0; ct < 2; ++ct)
                    acc[rt][ct] = __builtin_amdgcn_mfma_f32_16x16x32_bf16(
                        af[rt], bfr[ct], acc[rt][ct], 0, 0, 0);
        }
        __syncthreads();
        if (kp + 1 < K_DIM / 64)
            go_stage(Ag, Bg, As[0], Bs[0], kp * 64 + 64, w, lane);
        {
            short8 af[4], bfr[2];
            #pragma unroll
            for (int rt = 0; rt < 4; ++rt) af[rt] = *(const short8*)(aB[rt] + 4096);
            #pragma unroll
            for (int ct = 0; ct < 2; ++ct) bfr[ct] = *(const short8*)(bB[ct] + 2048);
            #pragma unroll
            for (int rt = 0; rt < 4; ++rt)
                #pragma unroll
                for (int ct = 0; ct < 2; ++ct)
                    acc[rt][ct] = __builtin_amdgcn_mfma_f32_16x16x32_bf16(
                        af[rt], bfr[ct], acc[rt][ct], 0, 0, 0);
        }
    }

    const int mbase = m0 + wr * 64, nbase = n0 + wc * 32;
    #pragma unroll
    for (int rt = 0; rt < 4; ++rt)
        #pragma unroll
        for (int ct = 0; ct < 2; ++ct)
            #pragma unroll
            for (int r = 0; r < 4; ++r)
                out[(size_t)(mbase + rt * 16 + qd * 4 + r) * DIM + nbase + ct * 16 + cl] =
                    acc[rt][ct][r];
}

// ---------------------------------------------------------------------------
// Flash attention v11: v10 + PAIR PROCESSING -- one __syncthreads + one
// vmcnt-drain per 128 k-positions (16 barriers vs 32). 4 K-buffers + 4
// V-buffers (64KB LDS, 2 blocks/CU = 128KB). Per pair-body: 2 tiles, 72
// MFMA + 2 exp-packs between barriers. PV-deferral: within a pair, PV(A)
// runs during tile B's phase; the persistent set carries tile B across the
// barrier. All LDS reads off 4 hoisted bases + offset: immediates
// (buffer stride 8192B, mt stride 2048B, max 30720 < 64K).
// ---------------------------------------------------------------------------
#define QK_MFMA(kfv, sdst)                                                      \
    _Pragma("unroll")                                                           \
    for (int mt = 0; mt < 4; ++mt)                                              \
        _Pragma("unroll")                                                       \
        for (int nt = 0; nt < 2; ++nt)                                          \
            sdst[mt][nt] = __builtin_amdgcn_mfma_f32_16x16x32_bf16(             \
                kfv[mt][0], qf[nt][0], fz, 0, 0, 0);                            \
    _Pragma("unroll")                                                           \
    for (int mt = 0; mt < 4; ++mt)                                              \
        _Pragma("unroll")                                                       \
        for (int nt = 0; nt < 2; ++nt)                                          \
            sdst[mt][nt] = __builtin_amdgcn_mfma_f32_16x16x32_bf16(             \
                kfv[mt][1], qf[nt][1], sdst[mt][nt], 0, 0, 0);

#define PV_MFMA(vfv, pfv)                                                       \
    _Pragma("unroll")                                                           \
    for (int kh = 0; kh < 2; ++kh)                                              \
        _Pragma("unroll")                                                       \
        for (int dt = 0; dt < 4; ++dt)                                          \
            _Pragma("unroll")                                                   \
            for (int nt = 0; nt < 2; ++nt)                                      \
                oaccT[dt][nt] = __builtin_amdgcn_mfma_f32_16x16x32_bf16(        \
                    vfv[dt][kh], pfv[nt][kh], oaccT[dt][nt], 0, 0, 0);

#define L_MFMA(pfv)                                                             \
    _Pragma("unroll")                                                           \
    for (int kh = 0; kh < 2; ++kh)                                              \
        _Pragma("unroll")                                                       \
        for (int nt = 0; nt < 2; ++nt)                                          \
            lacc[nt] = __builtin_amdgcn_mfma_f32_16x16x32_bf16(                 \
                onesA, pfv[nt][kh], lacc[nt], 0, 0, 0);

#define EXPPACK(sv, pfD)                                                        \
    _Pragma("unroll")                                                           \
    for (int nt = 0; nt < 2; ++nt) {                                            \
        unsigned int wr2[4][2];                                                 \
        _Pragma("unroll")                                                       \
        for (int mt = 0; mt < 4; ++mt) {                                        \
            const float e0 = __builtin_amdgcn_exp2f(sv[mt][nt][0]);             \
            const float e1 = __builtin_amdgcn_exp2f(sv[mt][nt][1]);             \
            const float e2 = __builtin_amdgcn_exp2f(sv[mt][nt][2]);             \
            const float e3 = __builtin_amdgcn_exp2f(sv[mt][nt][3]);             \
            union { __hip_bfloat162 h2; unsigned int u; } pk0, pk1;             \
            pk0.h2 = __float22bfloat162_rn(make_float2(e0, e1));                \
            pk1.h2 = __float22bfloat162_rn(make_float2(e2, e3));                \
            wr2[mt][0] = pk0.u;                                                 \
            wr2[mt][1] = pk1.u;                                                 \
        }                                                                       \
        _Pragma("unroll")                                                       \
        for (int kh = 0; kh < 2; ++kh) {                                        \
            union { unsigned int u[4]; short8 s8; } pu;                         \
            _Pragma("unroll")                                                   \
            for (int i = 0; i < 2; ++i) {                                       \
                unsigned int a  = wr2[2 * kh][i];                               \
                unsigned int bb = wr2[2 * kh + 1][i];                           \
                asm("v_permlane32_swap_b32 %0, %1" : "+v"(a), "+v"(bb));        \
                asm("v_permlane16_swap_b32 %0, %1" : "+v"(a), "+v"(bb));        \
                pu.u[i]     = a;                                                \
                pu.u[2 + i] = bb;                                               \
            }                                                                   \
            pfD[nt][kh] = pu.s8;                                                \
        }                                                                       \
    }

// One pair: tile A in buffer at BOFF, tile B at BOFF+4096 (ushort units).
// Consumes persistent set (pfC,vfC); produces (pfP,vfP).
#define PAIR_BODY(BOFF, pfC, vfC, pfP, vfP)                                     \
    {                                                                           \
        short8 kf[4][2], vfT[4][2], pfT[2][2];                                  \
        f32x4 s[4][2];                                                          \
        /* ---- tile A ---- */                                                  \
        _Pragma("unroll")                                                       \
        for (int mt = 0; mt < 4; ++mt) {                                        \
            kf[mt][0] = *(const short8*)(kb0 + (BOFF) + mt * 1024);             \
            kf[mt][1] = *(const short8*)(kb1 + (BOFF) + mt * 1024);             \
        }                                                                       \
        _Pragma("unroll")                                                       \
        for (int dt = 0; dt < 4; ++dt) {                                        \
            vfT[dt][0] = *(const short8*)(vb0 + (BOFF) + dt * 1024);            \
            vfT[dt][1] = *(const short8*)(vb1 + (BOFF) + dt * 1024);            \
        }                                                                       \
        __builtin_amdgcn_s_setprio(1);                                          \
        QK_MFMA(kf, s)                                                          \
        PV_MFMA(vfC, pfC)                                                       \
        __builtin_amdgcn_s_setprio(0);                                          \
        EXPPACK(s, pfT)                                                         \
        L_MFMA(pfT)                                                             \
        /* ---- tile B ---- */                                                  \
        _Pragma("unroll")                                                       \
        for (int mt = 0; mt < 4; ++mt) {                                        \
            kf[mt][0] = *(const short8*)(kb0 + (BOFF) + 4096 + mt * 1024);      \
            kf[mt][1] = *(const short8*)(kb1 + (BOFF) + 4096 + mt * 1024);      \
        }                                                                       \
        _Pragma("unroll")                                                       \
        for (int dt = 0; dt < 4; ++dt) {                                        \
            vfP[dt][0] = *(const short8*)(vb0 + (BOFF) + 4096 + dt * 1024);     \
            vfP[dt][1] = *(const short8*)(vb1 + (BOFF) + 4096 + dt * 1024);     \
        }                                                                       \
        __builtin_amdgcn_s_setprio(1);                                          \
        QK_MFMA(kf, s)                                                          \
        PV_MFMA(vfT, pfT)                                                       \
        __builtin_amdgcn_s_setprio(0);                                          \
        EXPPACK(s, pfP)                                                         \
        L_MFMA(pfP)                                                             \
    }

__global__ __launch_bounds__(256, 2)
void attn_mfma(const ushort_t* __restrict__ qb, const ushort_t* __restrict__ kb,
               const ushort_t* __restrict__ vt, ushort_t* __restrict__ ob)
{
    const int h = blockIdx.x;                 // fastest -> K/V sharers on one XCD
    const int b = blockIdx.y;
    const int qt = blockIdx.z;                // 0..15, 128 queries per block
    const int t = threadIdx.x;
    const int w = t >> 6, lane = t & 63;
    const int qd = lane >> 4, cl = lane & 15;

    __shared__ __align__(16) ushort_t Ks[4][64 * 64];   // 32KB
    __shared__ __align__(16) ushort_t Vs[4][64 * 64];   // 32KB

    const size_t bh = (size_t)b * NH + h;
    const ushort_t* qbase = qb + (bh * SEQ + qt * 128 + w * 32) * HD;
    const ushort_t* kbase = kb + bh * SEQ * HD;
    const ushort_t* vbase = vt + bh * (size_t)HD * SEQ;

    const int p0 = w * 128 + lane;
    const int r0a = p0 >> 3,  c0a = (p0 & 7) ^ (r0a & 7);
    const int p1 = p0 + 64;
    const int r1a = p1 >> 3,  c1a = (p1 & 7) ^ (r1a & 7);
    const int ldsoff0 = (w * 128) * 8;
    const int ldsoff1 = (w * 128 + 64) * 8;

    // staging pointers, advanced two 64-tiles per stage
    const ushort_t* kg0 = kbase + (size_t)r0a * HD + c0a * 8;
    const ushort_t* kg1 = kbase + (size_t)r1a * HD + c1a * 8;
    const ushort_t* vg0 = vbase + (size_t)r0a * SEQ + c0a * 8;
    const ushort_t* vg1 = vbase + (size_t)r1a * SEQ + c1a * 8;

    // hoisted LDS read bases (buffer 0); buffers 1..3 via +4096k immediates
    const int lo0 = (cl * 8 + (qd ^ (cl & 7))) * 8;
    const int lo1 = (cl * 8 + ((4 + qd) ^ (cl & 7))) * 8;
    const ushort_t* kb0 = Ks[0] + lo0; const ushort_t* kb1 = Ks[0] + lo1;
    const ushort_t* vb0 = Vs[0] + lo0; const ushort_t* vb1 = Vs[0] + lo1;

    short8 qf[2][2];
    #pragma unroll
    for (int nt = 0; nt < 2; ++nt)
        #pragma unroll
        for (int kh = 0; kh < 2; ++kh)
            qf[nt][kh] = *(const short8*)(qbase + (nt * 16 + cl) * HD + kh * 32 + qd * 8);

    const f32x4 fz = {0.f, 0.f, 0.f, 0.f};
    short8 onesA;
    #pragma unroll
    for (int e = 0; e < 8; ++e) onesA[e] = (short)0x3F80;   // bf16 1.0

    f32x4 oaccT[4][2];
    f32x4 lacc[2];
    #pragma unroll
    for (int dt = 0; dt < 4; ++dt)
        #pragma unroll
        for (int nt = 0; nt < 2; ++nt)
            #pragma unroll
            for (int r = 0; r < 4; ++r) oaccT[dt][nt][r] = 0.f;
    #pragma unroll
    for (int nt = 0; nt < 2; ++nt)
        #pragma unroll
        for (int r = 0; r < 4; ++r) lacc[nt][r] = 0.f;

    // persistent deferred-PV sets; S23 zeroed (first pair consumes it)
    short8 pf01[2][2], vf01[4][2], pf23[2][2], vf23[4][2];
    #pragma unroll
    for (int nt = 0; nt < 2; ++nt)
        #pragma unroll
        for (int kh = 0; kh < 2; ++kh)
            #pragma unroll
            for (int e = 0; e < 8; ++e) pf23[nt][kh][e] = 0;
    #pragma unroll
    for (int dt = 0; dt < 4; ++dt)
        #pragma unroll
        for (int kh = 0; kh < 2; ++kh)
            #pragma unroll
            for (int e = 0; e < 8; ++e) vf23[dt][kh][e] = 0;

    {   // stage tiles 0,1 into buffers 0,1
        ASYNC_COPY16(kg0,            (ushort_t*)Ks[0] + ldsoff0);
        ASYNC_COPY16(kg1,            (ushort_t*)Ks[0] + ldsoff1);
        ASYNC_COPY16(vg0,            (ushort_t*)Vs[0] + ldsoff0);
        ASYNC_COPY16(vg1,            (ushort_t*)Vs[0] + ldsoff1);
        ASYNC_COPY16(kg0 + 64 * HD,  (ushort_t*)Ks[1] + ldsoff0);
        ASYNC_COPY16(kg1 + 64 * HD,  (ushort_t*)Ks[1] + ldsoff1);
        ASYNC_COPY16(vg0 + 64,       (ushort_t*)Vs[1] + ldsoff0);
        ASYNC_COPY16(vg1 + 64,       (ushort_t*)Vs[1] + ldsoff1);
        kg0 += 128 * HD; kg1 += 128 * HD; vg0 += 128; vg1 += 128;
    }

    for (int q8 = 0; q8 < 8; ++q8) {
        // ======== pair A: tiles 4q8,4q8+1 in buffers {0,1} ========
        __syncthreads();
        {   // stage tiles 4q8+2,4q8+3 -> buffers {2,3} (always valid)
            ASYNC_COPY16(kg0,            (ushort_t*)Ks[2] + ldsoff0);
            ASYNC_COPY16(kg1,            (ushort_t*)Ks[2] + ldsoff1);
            ASYNC_COPY16(vg0,            (ushort_t*)Vs[2] + ldsoff0);
            ASYNC_COPY16(vg1,            (ushort_t*)Vs[2] + ldsoff1);
            ASYNC_COPY16(kg0 + 64 * HD,  (ushort_t*)Ks[3] + ldsoff0);
            ASYNC_COPY16(kg1 + 64 * HD,  (ushort_t*)Ks[3] + ldsoff1);
            ASYNC_COPY16(vg0 + 64,       (ushort_t*)Vs[3] + ldsoff0);
            ASYNC_COPY16(vg1 + 64,       (ushort_t*)Vs[3] + ldsoff1);
            kg0 += 128 * HD; kg1 += 128 * HD; vg0 += 128; vg1 += 128;
        }
        PAIR_BODY(0, pf23, vf23, pf01, vf01)

        // ======== pair B: tiles 4q8+2,4q8+3 in buffers {2,3} ========
        __syncthreads();
        if (q8 + 1 < 8) {   // stage tiles 4q8+4,4q8+5 -> buffers {0,1}
            ASYNC_COPY16(kg0,            (ushort_t*)Ks[0] + ldsoff0);
            ASYNC_COPY16(kg1,            (ushort_t*)Ks[0] + ldsoff1);
            ASYNC_COPY16(vg0,            (ushort_t*)Vs[0] + ldsoff0);
            ASYNC_COPY16(vg1,            (ushort_t*)Vs[0] + ldsoff1);
            ASYNC_COPY16(kg0 + 64 * HD,  (ushort_t*)Ks[1] + ldsoff0);
            ASYNC_COPY16(kg1 + 64 * HD,  (ushort_t*)Ks[1] + ldsoff1);
            ASYNC_COPY16(vg0 + 64,       (ushort_t*)Vs[1] + ldsoff0);
            ASYNC_COPY16(vg1 + 64,       (ushort_t*)Vs[1] + ldsoff1);
            kg0 += 128 * HD; kg1 += 128 * HD; vg0 += 128; vg1 += 128;
        }
        PAIR_BODY(8192, pf01, vf01, pf23, vf23)
    }

    // tail PV for the last tile (pair B of q8=7 produced pf23/vf23)
    PV_MFMA(vf23, pf23)

    // ---- epilogue: l comes straight from lacc (all rows equal) ----
    #pragma unroll
    for (int nt = 0; nt < 2; ++nt) {
        const float inv = 1.0f / lacc[nt][0];
        const int query = qt * 128 + w * 32 + nt * 16 + cl;
        ushort_t* op = ob + ((size_t)b * SEQ + query) * DIM + h * HD;
        #pragma unroll
        for (int dt = 0; dt < 4; ++dt) {
            short4v o4;
            #pragma unroll
            for (int r = 0; r < 4; ++r) o4[r] = (short)f2b(oaccT[dt][nt][r] * inv);
            *(short4v*)(op + dt * 16 + qd * 4) = o4;
        }
    }
}

// ---------------------------------------------------------------------------
extern "C" void kernel_launch(void* const* d_in, const int* in_sizes, int n_in,
                              void* d_out, int out_size, void* d_ws, size_t ws_size,
                              hipStream_t stream)
{
    const float* x     = (const float*)d_in[0];
    const float* cosb  = (const float*)d_in[1];
    const float* sinb  = (const float*)d_in[2];
    const float* w_qkv = (const float*)d_in[3];
    const float* w_out = (const float*)d_in[4];
    float* out = (float*)d_out;

    // workspace layout (peak 48MB, no aliasing hazards):
    //  [0,8)   qb   [8,16) kb   [16,24) vt   [24,26) wob
    //  [26,34) ob   [34,42) xb  [42,48) wqb
    constexpr size_t MB = 1u << 20;
    char* ws = (char*)d_ws;
    ushort_t* qb  = (ushort_t*)(ws);
    ushort_t* kb  = (ushort_t*)(ws + 8 * MB);
    ushort_t* vt  = (ushort_t*)(ws + 16 * MB);
    ushort_t* wob = (ushort_t*)(ws + 24 * MB);
    ushort_t* ob  = (ushort_t*)(ws + 26 * MB);
    ushort_t* xb  = (ushort_t*)(ws + 34 * MB);
    ushort_t* wqb = (ushort_t*)(ws + 42 * MB);

    prep<<<3072, 256, 0, stream>>>(x, w_qkv, w_out, xb, wqb, wob);
    gemm_qkv_mfma<<<dim3(24, 32), 256, 0, stream>>>(xb, wqb, qb, kb, vt, cosb, sinb);
    attn_mfma<<<dim3(16, 2, 16), 256, 0, stream>>>(qb, kb, vt, ob);
    gemm_out_mfma<<<dim3(16, 32), 256, 0, stream>>>(ob, wob, out);
}

// Round 6
// 186.768 us; speedup vs baseline: 1.1043x; 1.0214x over previous
//
#include <hip/hip_runtime.h>
#include <hip/hip_bf16.h>

#define BATCH 2
#define SEQ   2048
#define DIM   1024
#define NH    16
#define HD    64
#define K_DIM 1024

typedef __attribute__((ext_vector_type(8))) short short8;
typedef __attribute__((ext_vector_type(4))) short short4v;
typedef __attribute__((ext_vector_type(4))) float f32x4;
typedef unsigned short ushort_t;

// fp32 -> bf16 bits, round-to-nearest-even
__device__ __forceinline__ unsigned short f2b(float x) {
    unsigned int u = __float_as_uint(x);
    u += 0x7FFFu + ((u >> 16) & 1u);
    return (unsigned short)(u >> 16);
}

// async global->LDS, 16B per lane; LDS dest = wave-uniform base + lane*16
#define ASYNC_COPY16(gp, lp) \
    __builtin_amdgcn_global_load_lds((const __attribute__((address_space(1))) void*)(gp), \
                                     (__attribute__((address_space(3))) void*)(lp), 16, 0, 0)

// ---------------------------------------------------------------------------
// Merged prep kernel: [0,1024) cast x; [1024,2560) transpose w_qkv;
// [2560,3072) transpose w_out.
// ---------------------------------------------------------------------------
__global__ __launch_bounds__(256)
void prep(const float* __restrict__ x, const float* __restrict__ w_qkv,
          const float* __restrict__ w_out, ushort_t* __restrict__ xb,
          ushort_t* __restrict__ wqb, ushort_t* __restrict__ wob)
{
    const int bid = blockIdx.x;
    if (bid < 1024) {
        constexpr int n4 = (BATCH * SEQ * DIM) / 4;
        int i = bid * 256 + threadIdx.x;
        for (; i < n4; i += 1024 * 256) {
            float4 v = ((const float4*)x)[i];
            short4v o;
            o[0] = (short)f2b(v.x); o[1] = (short)f2b(v.y);
            o[2] = (short)f2b(v.z); o[3] = (short)f2b(v.w);
            ((short4v*)xb)[i] = o;
        }
    } else {
        const int lane = threadIdx.x & 63;
        const float* src; ushort_t* dst; int N, job;
        if (bid < 2560) { src = w_qkv; dst = wqb; N = 3072; job = (bid - 1024) * 4 + (threadIdx.x >> 6); }
        else            { src = w_out; dst = wob; N = 1024; job = (bid - 2560) * 4 + (threadIdx.x >> 6); }
        const int jn = (N == 3072) ? (job % 48) : (job % 16);
        const int jk = (N == 3072) ? (job / 48) : (job / 16);
        const int n  = jn * 64 + lane;
        const int k0 = jk * 8;
        short8 o;
        #pragma unroll
        for (int j = 0; j < 8; ++j) o[j] = (short)f2b(src[(size_t)(k0 + j) * N + n]);
        *(short8*)(dst + (size_t)n * K_DIM + k0) = o;
    }
}

// ---------------------------------------------------------------------------
// 128x128 MFMA GEMM mainloop: BK=32, double-buffered LDS, post-barrier
// prefetch, chunk-XOR swizzle. k-loop unrolled x2 with STATIC buffer
// addressing. R6 order: ds_read FIRST, then stage (8-phase template order) --
// critical-path LDS reads issue before the staging VMEM burst.
// ---------------------------------------------------------------------------
__device__ __forceinline__ void gemm_stage(const ushort_t* __restrict__ Ag,
                                           const ushort_t* __restrict__ Bg,
                                           ushort_t* As, ushort_t* Bs,
                                           int k0, int w, int r0, int c0)
{
    ASYNC_COPY16(Ag + (size_t)r0 * K_DIM + k0 + c0 * 8,        As + w * 512);
    ASYNC_COPY16(Ag + (size_t)(64 + r0) * K_DIM + k0 + c0 * 8, As + w * 512 + 2048);
    ASYNC_COPY16(Bg + (size_t)r0 * K_DIM + k0 + c0 * 8,        Bs + w * 512);
    ASYNC_COPY16(Bg + (size_t)(64 + r0) * K_DIM + k0 + c0 * 8, Bs + w * 512 + 2048);
}

__device__ __forceinline__ void mfma_gemm_tile(
    const ushort_t* __restrict__ Ag, const ushort_t* __restrict__ Bg,
    ushort_t (&As)[2][128 * 32], ushort_t (&Bs)[2][128 * 32], f32x4 acc[4][4])
{
    const int t = threadIdx.x;
    const int w = t >> 6, lane = t & 63;
    const int qd = lane >> 4, cl = lane & 15;
    const int p0 = w * 64 + lane;
    const int r0 = p0 >> 2;
    const int c0 = (p0 & 3) ^ (r0 & 3);

    // hoisted LDS read bases (buffer 0; buffer 1 = +4096 ushorts = 8192B imm)
    const ushort_t* aB[4];
    const ushort_t* bB[4];
    #pragma unroll
    for (int rt = 0; rt < 4; ++rt) {
        const int row = (w >> 1) * 64 + rt * 16 + cl;
        aB[rt] = As[0] + row * 32 + ((qd ^ (row & 3)) * 8);
    }
    #pragma unroll
    for (int ct = 0; ct < 4; ++ct) {
        const int col = (w & 1) * 64 + ct * 16 + cl;
        bB[ct] = Bs[0] + col * 32 + ((qd ^ (col & 3)) * 8);
    }

    gemm_stage(Ag, Bg, As[0], Bs[0], 0, w, r0, c0);

    for (int kp = 0; kp < K_DIM / 64; ++kp) {
        // ---- even step (buffer 0), k = kp*64 ----
        __syncthreads();
        {
            short8 af[4], bfr[4];
            #pragma unroll
            for (int rt = 0; rt < 4; ++rt) af[rt] = *(const short8*)(aB[rt]);
            #pragma unroll
            for (int ct = 0; ct < 4; ++ct) bfr[ct] = *(const short8*)(bB[ct]);
            gemm_stage(Ag, Bg, As[1], Bs[1], kp * 64 + 32, w, r0, c0);
            #pragma unroll
            for (int rt = 0; rt < 4; ++rt)
                #pragma unroll
                for (int ct = 0; ct < 4; ++ct)
                    acc[rt][ct] = __builtin_amdgcn_mfma_f32_16x16x32_bf16(
                        af[rt], bfr[ct], acc[rt][ct], 0, 0, 0);
        }
        // ---- odd step (buffer 1), k = kp*64+32 ----
        __syncthreads();
        {
            short8 af[4], bfr[4];
            #pragma unroll
            for (int rt = 0; rt < 4; ++rt) af[rt] = *(const short8*)(aB[rt] + 4096);
            #pragma unroll
            for (int ct = 0; ct < 4; ++ct) bfr[ct] = *(const short8*)(bB[ct] + 4096);
            if (kp + 1 < K_DIM / 64)
                gemm_stage(Ag, Bg, As[0], Bs[0], kp * 64 + 64, w, r0, c0);
            #pragma unroll
            for (int rt = 0; rt < 4; ++rt)
                #pragma unroll
                for (int ct = 0; ct < 4; ++ct)
                    acc[rt][ct] = __builtin_amdgcn_mfma_f32_16x16x32_bf16(
                        af[rt], bfr[ct], acc[rt][ct], 0, 0, 0);
        }
    }
}

// ---------------------------------------------------------------------------
// GEMM1: qkv = xb @ wqb^T with fused RoPE + bf16 stores (d' = cl*4+ct perm).
// ---------------------------------------------------------------------------
__global__ __launch_bounds__(256, 3)
void gemm_qkv_mfma(const ushort_t* __restrict__ xb, const ushort_t* __restrict__ wqb,
                   ushort_t* __restrict__ qb, ushort_t* __restrict__ kb,
                   ushort_t* __restrict__ vt,
                   const float* __restrict__ cosb, const float* __restrict__ sinb)
{
    __shared__ __align__(16) ushort_t As[2][128 * 32];
    __shared__ __align__(16) ushort_t Bs[2][128 * 32];
    const int m0 = blockIdx.y * 128, n0 = blockIdx.x * 128;

    f32x4 acc[4][4];
    #pragma unroll
    for (int i = 0; i < 4; ++i)
        #pragma unroll
        for (int j = 0; j < 4; ++j)
            #pragma unroll
            for (int r = 0; r < 4; ++r) acc[i][j][r] = 0.f;

    mfma_gemm_tile(xb + (size_t)m0 * K_DIM, wqb + (size_t)n0 * K_DIM, As, Bs, acc);

    const int t = threadIdx.x, w = t >> 6, lane = t & 63;
    const int qd = lane >> 4, cl = lane & 15;
    const int b = m0 >> 11;
    const int lbase = (m0 & 2047) + (w >> 1) * 64;
    const int region = blockIdx.x >> 3;              // 0=q, 1=k, 2=v
    const int h = (blockIdx.x & 7) * 2 + (w & 1);

    if (region < 2) {
        ushort_t* dst = region ? kb : qb;
        const float sc = region ? 1.0f : 0.18033688011111234f;  // 0.125*log2(e)
        #pragma unroll
        for (int rt = 0; rt < 4; ++rt) {
            #pragma unroll
            for (int r = 0; r < 4; ++r) {
                const int l = lbase + rt * 16 + qd * 4 + r;
                const float c0 = cosb[l * HD + cl],      s0 = sinb[l * HD + cl];
                const float c1 = cosb[l * HD + 16 + cl], s1 = sinb[l * HD + 16 + cl];
                const float v0 = acc[rt][0][r] * c0 - acc[rt][2][r] * s0;
                const float v1 = acc[rt][1][r] * c1 - acc[rt][3][r] * s1;
                const float v2 = acc[rt][2][r] * c0 + acc[rt][0][r] * s0;
                const float v3 = acc[rt][3][r] * c1 + acc[rt][1][r] * s1;
                short4v o4;
                o4[0] = (short)f2b(v0 * sc);
                o4[1] = (short)f2b(v1 * sc);
                o4[2] = (short)f2b(v2 * sc);
                o4[3] = (short)f2b(v3 * sc);
                *(short4v*)(dst + (((size_t)b * NH + h) * SEQ + l) * HD + cl * 4) = o4;
            }
        }
    } else {
        #pragma unroll
        for (int rt = 0; rt < 4; ++rt)
            #pragma unroll
            for (int ct = 0; ct < 4; ++ct) {
                const int d = ct * 16 + cl;
                const int l = lbase + rt * 16 + qd * 4;
                short4v o4;
                #pragma unroll
                for (int r = 0; r < 4; ++r) o4[r] = (short)f2b(acc[rt][ct][r]);
                *(short4v*)(vt + (((size_t)b * NH + h) * HD + d) * SEQ + l) = o4;
            }
    }
}

// ---------------------------------------------------------------------------
// GEMM2: out = ob @ wob^T, 128x64 tiles (512 blocks -> 2 blocks/CU), BK=32
// dbuf staging, fp32 store. x2 unroll, static buffers, ds_read-first order.
// ---------------------------------------------------------------------------
__device__ __forceinline__ void go_stage(const ushort_t* __restrict__ Ag,
                                         const ushort_t* __restrict__ Bg,
                                         ushort_t* As, ushort_t* Bs,
                                         int k0, int w, int lane)
{
    #pragma unroll
    for (int j = 0; j < 2; ++j) {
        const int r = w * 32 + j * 16 + (lane >> 2);
        const int c = (lane & 3) ^ (r & 3);
        ASYNC_COPY16(Ag + (size_t)r * K_DIM + k0 + c * 8, As + (w * 128 + j * 64) * 8);
    }
    const int rb = w * 16 + (lane >> 2);
    const int cb = (lane & 3) ^ (rb & 3);
    ASYNC_COPY16(Bg + (size_t)rb * K_DIM + k0 + cb * 8, Bs + (w * 64) * 8);
}

__global__ __launch_bounds__(256, 3)
void gemm_out_mfma(const ushort_t* __restrict__ ob, const ushort_t* __restrict__ wob,
                   float* __restrict__ out)
{
    __shared__ __align__(16) ushort_t As[2][128 * 32];
    __shared__ __align__(16) ushort_t Bs[2][64 * 32];
    const int m0 = blockIdx.y * 128, n0 = blockIdx.x * 64;
    const int t = threadIdx.x;
    const int w = t >> 6, lane = t & 63;
    const int qd = lane >> 4, cl = lane & 15;
    const int wr = w >> 1, wc = w & 1;

    f32x4 acc[4][2];
    #pragma unroll
    for (int i = 0; i < 4; ++i)
        #pragma unroll
        for (int j = 0; j < 2; ++j)
            #pragma unroll
            for (int r = 0; r < 4; ++r) acc[i][j][r] = 0.f;

    const ushort_t* Ag = ob  + (size_t)m0 * K_DIM;
    const ushort_t* Bg = wob + (size_t)n0 * K_DIM;

    const ushort_t* aB[4];
    const ushort_t* bB[2];
    #pragma unroll
    for (int rt = 0; rt < 4; ++rt) {
        const int row = wr * 64 + rt * 16 + cl;
        aB[rt] = As[0] + row * 32 + ((qd ^ (row & 3)) * 8);
    }
    #pragma unroll
    for (int ct = 0; ct < 2; ++ct) {
        const int col = wc * 32 + ct * 16 + cl;
        bB[ct] = Bs[0] + col * 32 + ((qd ^ (col & 3)) * 8);
    }

    go_stage(Ag, Bg, As[0], Bs[0], 0, w, lane);

    for (int kp = 0; kp < K_DIM / 64; ++kp) {
        __syncthreads();
        {
            short8 af[4], bfr[2];
            #pragma unroll
            for (int rt = 0; rt < 4; ++rt) af[rt] = *(const short8*)(aB[rt]);
            #pragma unroll
            for (int ct = 0; ct < 2; ++ct) bfr[ct] = *(const short8*)(bB[ct]);
            go_stage(Ag, Bg, As[1], Bs[1], kp * 64 + 32, w, lane);
            #pragma unroll
            for (int rt = 0; rt < 4; ++rt)
                #pragma unroll
                for (int ct = 0; ct < 2; ++ct)
                    acc[rt][ct] = __builtin_amdgcn_mfma_f32_16x16x32_bf16(
                        af[rt], bfr[ct], acc[rt][ct], 0, 0, 0);
        }
        __syncthreads();
        {
            short8 af[4], bfr[2];
            #pragma unroll
            for (int rt = 0; rt < 4; ++rt) af[rt] = *(const short8*)(aB[rt] + 4096);
            #pragma unroll
            for (int ct = 0; ct < 2; ++ct) bfr[ct] = *(const short8*)(bB[ct] + 2048);
            if (kp + 1 < K_DIM / 64)
                go_stage(Ag, Bg, As[0], Bs[0], kp * 64 + 64, w, lane);
            #pragma unroll
            for (int rt = 0; rt < 4; ++rt)
                #pragma unroll
                for (int ct = 0; ct < 2; ++ct)
                    acc[rt][ct] = __builtin_amdgcn_mfma_f32_16x16x32_bf16(
                        af[rt], bfr[ct], acc[rt][ct], 0, 0, 0);
        }
    }

    const int mbase = m0 + wr * 64, nbase = n0 + wc * 32;
    #pragma unroll
    for (int rt = 0; rt < 4; ++rt)
        #pragma unroll
        for (int ct = 0; ct < 2; ++ct)
            #pragma unroll
            for (int r = 0; r < 4; ++r)
                out[(size_t)(mbase + rt * 16 + qd * 4 + r) * DIM + nbase + ct * 16 + cl] =
                    acc[rt][ct][r];
}

// ---------------------------------------------------------------------------
// Flash attention v11 (RESTORED verified version): pair processing -- one
// __syncthreads + one vmcnt-drain per 128 k-positions. 4 K-buffers + 4
// V-buffers (64KB LDS, 2 blocks/CU). Per pair-body: 2 tiles, 72 MFMA + 2
// exp-packs between barriers. PV-deferral: within a pair, PV(A) runs during
// tile B's phase; the persistent set carries tile B across the barrier.
// All LDS reads off 4 hoisted bases + offset: immediates.
// (v12's V-direct-from-global FAILED correctness on HW despite on-paper
// equivalence -- reverted; do not retry without an isolated register-dump
// A/B probe of the two V paths.)
// ---------------------------------------------------------------------------
#define QK_MFMA(kfv, sdst)                                                      \
    _Pragma("unroll")                                                           \
    for (int mt = 0; mt < 4; ++mt)                                              \
        _Pragma("unroll")                                                       \
        for (int nt = 0; nt < 2; ++nt)                                          \
            sdst[mt][nt] = __builtin_amdgcn_mfma_f32_16x16x32_bf16(             \
                kfv[mt][0], qf[nt][0], fz, 0, 0, 0);                            \
    _Pragma("unroll")                                                           \
    for (int mt = 0; mt < 4; ++mt)                                              \
        _Pragma("unroll")                                                       \
        for (int nt = 0; nt < 2; ++nt)                                          \
            sdst[mt][nt] = __builtin_amdgcn_mfma_f32_16x16x32_bf16(             \
                kfv[mt][1], qf[nt][1], sdst[mt][nt], 0, 0, 0);

#define PV_MFMA(vfv, pfv)                                                       \
    _Pragma("unroll")                                                           \
    for (int kh = 0; kh < 2; ++kh)                                              \
        _Pragma("unroll")                                                       \
        for (int dt = 0; dt < 4; ++dt)                                          \
            _Pragma("unroll")                                                   \
            for (int nt = 0; nt < 2; ++nt)                                      \
                oaccT[dt][nt] = __builtin_amdgcn_mfma_f32_16x16x32_bf16(        \
                    vfv[dt][kh], pfv[nt][kh], oaccT[dt][nt], 0, 0, 0);

#define L_MFMA(pfv)                                                             \
    _Pragma("unroll")                                                           \
    for (int kh = 0; kh < 2; ++kh)                                              \
        _Pragma("unroll")                                                       \
        for (int nt = 0; nt < 2; ++nt)                                          \
            lacc[nt] = __builtin_amdgcn_mfma_f32_16x16x32_bf16(                 \
                onesA, pfv[nt][kh], lacc[nt], 0, 0, 0);

#define EXPPACK(sv, pfD)                                                        \
    _Pragma("unroll")                                                           \
    for (int nt = 0; nt < 2; ++nt) {                                            \
        unsigned int wr2[4][2];                                                 \
        _Pragma("unroll")                                                       \
        for (int mt = 0; mt < 4; ++mt) {                                        \
            const float e0 = __builtin_amdgcn_exp2f(sv[mt][nt][0]);             \
            const float e1 = __builtin_amdgcn_exp2f(sv[mt][nt][1]);             \
            const float e2 = __builtin_amdgcn_exp2f(sv[mt][nt][2]);             \
            const float e3 = __builtin_amdgcn_exp2f(sv[mt][nt][3]);             \
            union { __hip_bfloat162 h2; unsigned int u; } pk0, pk1;             \
            pk0.h2 = __float22bfloat162_rn(make_float2(e0, e1));                \
            pk1.h2 = __float22bfloat162_rn(make_float2(e2, e3));                \
            wr2[mt][0] = pk0.u;                                                 \
            wr2[mt][1] = pk1.u;                                                 \
        }                                                                       \
        _Pragma("unroll")                                                       \
        for (int kh = 0; kh < 2; ++kh) {                                        \
            union { unsigned int u[4]; short8 s8; } pu;                         \
            _Pragma("unroll")                                                   \
            for (int i = 0; i < 2; ++i) {                                       \
                unsigned int a  = wr2[2 * kh][i];                               \
                unsigned int bb = wr2[2 * kh + 1][i];                           \
                asm("v_permlane32_swap_b32 %0, %1" : "+v"(a), "+v"(bb));        \
                asm("v_permlane16_swap_b32 %0, %1" : "+v"(a), "+v"(bb));        \
                pu.u[i]     = a;                                                \
                pu.u[2 + i] = bb;                                               \
            }                                                                   \
            pfD[nt][kh] = pu.s8;                                                \
        }                                                                       \
    }

// One pair: tile A in buffer at BOFF, tile B at BOFF+4096 (ushort units).
// Consumes persistent set (pfC,vfC); produces (pfP,vfP).
#define PAIR_BODY(BOFF, pfC, vfC, pfP, vfP)                                     \
    {                                                                           \
        short8 kf[4][2], vfT[4][2], pfT[2][2];                                  \
        f32x4 s[4][2];                                                          \
        /* ---- tile A ---- */                                                  \
        _Pragma("unroll")                                                       \
        for (int mt = 0; mt < 4; ++mt) {                                        \
            kf[mt][0] = *(const short8*)(kb0 + (BOFF) + mt * 1024);             \
            kf[mt][1] = *(const short8*)(kb1 + (BOFF) + mt * 1024);             \
        }                                                                       \
        _Pragma("unroll")                                                       \
        for (int dt = 0; dt < 4; ++dt) {                                        \
            vfT[dt][0] = *(const short8*)(vb0 + (BOFF) + dt * 1024);            \
            vfT[dt][1] = *(const short8*)(vb1 + (BOFF) + dt * 1024);            \
        }                                                                       \
        __builtin_amdgcn_s_setprio(1);                                          \
        QK_MFMA(kf, s)                                                          \
        PV_MFMA(vfC, pfC)                                                       \
        __builtin_amdgcn_s_setprio(0);                                          \
        EXPPACK(s, pfT)                                                         \
        L_MFMA(pfT)                                                             \
        /* ---- tile B ---- */                                                  \
        _Pragma("unroll")                                                       \
        for (int mt = 0; mt < 4; ++mt) {                                        \
            kf[mt][0] = *(const short8*)(kb0 + (BOFF) + 4096 + mt * 1024);      \
            kf[mt][1] = *(const short8*)(kb1 + (BOFF) + 4096 + mt * 1024);      \
        }                                                                       \
        _Pragma("unroll")                                                       \
        for (int dt = 0; dt < 4; ++dt) {                                        \
            vfP[dt][0] = *(const short8*)(vb0 + (BOFF) + 4096 + dt * 1024);     \
            vfP[dt][1] = *(const short8*)(vb1 + (BOFF) + 4096 + dt * 1024);     \
        }                                                                       \
        __builtin_amdgcn_s_setprio(1);                                          \
        QK_MFMA(kf, s)                                                          \
        PV_MFMA(vfT, pfT)                                                       \
        __builtin_amdgcn_s_setprio(0);                                          \
        EXPPACK(s, pfP)                                                         \
        L_MFMA(pfP)                                                             \
    }

__global__ __launch_bounds__(256, 2)
void attn_mfma(const ushort_t* __restrict__ qb, const ushort_t* __restrict__ kb,
               const ushort_t* __restrict__ vt, ushort_t* __restrict__ ob)
{
    const int h = blockIdx.x;                 // fastest -> K/V sharers on one XCD
    const int b = blockIdx.y;
    const int qt = blockIdx.z;                // 0..15, 128 queries per block
    const int t = threadIdx.x;
    const int w = t >> 6, lane = t & 63;
    const int qd = lane >> 4, cl = lane & 15;

    __shared__ __align__(16) ushort_t Ks[4][64 * 64];   // 32KB
    __shared__ __align__(16) ushort_t Vs[4][64 * 64];   // 32KB

    const size_t bh = (size_t)b * NH + h;
    const ushort_t* qbase = qb + (bh * SEQ + qt * 128 + w * 32) * HD;
    const ushort_t* kbase = kb + bh * SEQ * HD;
    const ushort_t* vbase = vt + bh * (size_t)HD * SEQ;

    const int p0 = w * 128 + lane;
    const int r0a = p0 >> 3,  c0a = (p0 & 7) ^ (r0a & 7);
    const int p1 = p0 + 64;
    const int r1a = p1 >> 3,  c1a = (p1 & 7) ^ (r1a & 7);
    const int ldsoff0 = (w * 128) * 8;
    const int ldsoff1 = (w * 128 + 64) * 8;

    // staging pointers, advanced two 64-tiles per stage
    const ushort_t* kg0 = kbase + (size_t)r0a * HD + c0a * 8;
    const ushort_t* kg1 = kbase + (size_t)r1a * HD + c1a * 8;
    const ushort_t* vg0 = vbase + (size_t)r0a * SEQ + c0a * 8;
    const ushort_t* vg1 = vbase + (size_t)r1a * SEQ + c1a * 8;

    // hoisted LDS read bases (buffer 0); buffers 1..3 via +4096k immediates
    const int lo0 = (cl * 8 + (qd ^ (cl & 7))) * 8;
    const int lo1 = (cl * 8 + ((4 + qd) ^ (cl & 7))) * 8;
    const ushort_t* kb0 = Ks[0] + lo0; const ushort_t* kb1 = Ks[0] + lo1;
    const ushort_t* vb0 = Vs[0] + lo0; const ushort_t* vb1 = Vs[0] + lo1;

    short8 qf[2][2];
    #pragma unroll
    for (int nt = 0; nt < 2; ++nt)
        #pragma unroll
        for (int kh = 0; kh < 2; ++kh)
            qf[nt][kh] = *(const short8*)(qbase + (nt * 16 + cl) * HD + kh * 32 + qd * 8);

    const f32x4 fz = {0.f, 0.f, 0.f, 0.f};
    short8 onesA;
    #pragma unroll
    for (int e = 0; e < 8; ++e) onesA[e] = (short)0x3F80;   // bf16 1.0

    f32x4 oaccT[4][2];
    f32x4 lacc[2];
    #pragma unroll
    for (int dt = 0; dt < 4; ++dt)
        #pragma unroll
        for (int nt = 0; nt < 2; ++nt)
            #pragma unroll
            for (int r = 0; r < 4; ++r) oaccT[dt][nt][r] = 0.f;
    #pragma unroll
    for (int nt = 0; nt < 2; ++nt)
        #pragma unroll
        for (int r = 0; r < 4; ++r) lacc[nt][r] = 0.f;

    // persistent deferred-PV sets; set-23 zeroed (first pair consumes it)
    short8 pf01[2][2], vf01[4][2], pf23[2][2], vf23[4][2];
    #pragma unroll
    for (int nt = 0; nt < 2; ++nt)
        #pragma unroll
        for (int kh = 0; kh < 2; ++kh)
            #pragma unroll
            for (int e = 0; e < 8; ++e) pf23[nt][kh][e] = 0;
    #pragma unroll
    for (int dt = 0; dt < 4; ++dt)
        #pragma unroll
        for (int kh = 0; kh < 2; ++kh)
            #pragma unroll
            for (int e = 0; e < 8; ++e) vf23[dt][kh][e] = 0;

    {   // stage tiles 0,1 into buffers 0,1
        ASYNC_COPY16(kg0,            (ushort_t*)Ks[0] + ldsoff0);
        ASYNC_COPY16(kg1,            (ushort_t*)Ks[0] + ldsoff1);
        ASYNC_COPY16(vg0,            (ushort_t*)Vs[0] + ldsoff0);
        ASYNC_COPY16(vg1,            (ushort_t*)Vs[0] + ldsoff1);
        ASYNC_COPY16(kg0 + 64 * HD,  (ushort_t*)Ks[1] + ldsoff0);
        ASYNC_COPY16(kg1 + 64 * HD,  (ushort_t*)Ks[1] + ldsoff1);
        ASYNC_COPY16(vg0 + 64,       (ushort_t*)Vs[1] + ldsoff0);
        ASYNC_COPY16(vg1 + 64,       (ushort_t*)Vs[1] + ldsoff1);
        kg0 += 128 * HD; kg1 += 128 * HD; vg0 += 128; vg1 += 128;
    }

    for (int q8 = 0; q8 < 8; ++q8) {
        // ======== pair A: tiles 4q8,4q8+1 in buffers {0,1} ========
        __syncthreads();
        {   // stage tiles 4q8+2,4q8+3 -> buffers {2,3} (always valid)
            ASYNC_COPY16(kg0,            (ushort_t*)Ks[2] + ldsoff0);
            ASYNC_COPY16(kg1,            (ushort_t*)Ks[2] + ldsoff1);
            ASYNC_COPY16(vg0,            (ushort_t*)Vs[2] + ldsoff0);
            ASYNC_COPY16(vg1,            (ushort_t*)Vs[2] + ldsoff1);
            ASYNC_COPY16(kg0 + 64 * HD,  (ushort_t*)Ks[3] + ldsoff0);
            ASYNC_COPY16(kg1 + 64 * HD,  (ushort_t*)Ks[3] + ldsoff1);
            ASYNC_COPY16(vg0 + 64,       (ushort_t*)Vs[3] + ldsoff0);
            ASYNC_COPY16(vg1 + 64,       (ushort_t*)Vs[3] + ldsoff1);
            kg0 += 128 * HD; kg1 += 128 * HD; vg0 += 128; vg1 += 128;
        }
        PAIR_BODY(0, pf23, vf23, pf01, vf01)

        // ======== pair B: tiles 4q8+2,4q8+3 in buffers {2,3} ========
        __syncthreads();
        if (q8 + 1 < 8) {   // stage tiles 4q8+4,4q8+5 -> buffers {0,1}
            ASYNC_COPY16(kg0,            (ushort_t*)Ks[0] + ldsoff0);
            ASYNC_COPY16(kg1,            (ushort_t*)Ks[0] + ldsoff1);
            ASYNC_COPY16(vg0,            (ushort_t*)Vs[0] + ldsoff0);
            ASYNC_COPY16(vg1,            (ushort_t*)Vs[0] + ldsoff1);
            ASYNC_COPY16(kg0 + 64 * HD,  (ushort_t*)Ks[1] + ldsoff0);
            ASYNC_COPY16(kg1 + 64 * HD,  (ushort_t*)Ks[1] + ldsoff1);
            ASYNC_COPY16(vg0 + 64,       (ushort_t*)Vs[1] + ldsoff0);
            ASYNC_COPY16(vg1 + 64,       (ushort_t*)Vs[1] + ldsoff1);
            kg0 += 128 * HD; kg1 += 128 * HD; vg0 += 128; vg1 += 128;
        }
        PAIR_BODY(8192, pf01, vf01, pf23, vf23)
    }

    // tail PV for the last tile (pair B of q8=7 produced pf23/vf23)
    PV_MFMA(vf23, pf23)

    // ---- epilogue: l comes straight from lacc (all rows equal) ----
    #pragma unroll
    for (int nt = 0; nt < 2; ++nt) {
        const float inv = 1.0f / lacc[nt][0];
        const int query = qt * 128 + w * 32 + nt * 16 + cl;
        ushort_t* op = ob + ((size_t)b * SEQ + query) * DIM + h * HD;
        #pragma unroll
        for (int dt = 0; dt < 4; ++dt) {
            short4v o4;
            #pragma unroll
            for (int r = 0; r < 4; ++r) o4[r] = (short)f2b(oaccT[dt][nt][r] * inv);
            *(short4v*)(op + dt * 16 + qd * 4) = o4;
        }
    }
}

// ---------------------------------------------------------------------------
extern "C" void kernel_launch(void* const* d_in, const int* in_sizes, int n_in,
                              void* d_out, int out_size, void* d_ws, size_t ws_size,
                              hipStream_t stream)
{
    const float* x     = (const float*)d_in[0];
    const float* cosb  = (const float*)d_in[1];
    const float* sinb  = (const float*)d_in[2];
    const float* w_qkv = (const float*)d_in[3];
    const float* w_out = (const float*)d_in[4];
    float* out = (float*)d_out;

    // workspace layout (peak 48MB, no aliasing hazards):
    //  [0,8)   qb   [8,16) kb   [16,24) vt   [24,26) wob
    //  [26,34) ob   [34,42) xb  [42,48) wqb
    constexpr size_t MB = 1u << 20;
    char* ws = (char*)d_ws;
    ushort_t* qb  = (ushort_t*)(ws);
    ushort_t* kb  = (ushort_t*)(ws + 8 * MB);
    ushort_t* vt  = (ushort_t*)(ws + 16 * MB);
    ushort_t* wob = (ushort_t*)(ws + 24 * MB);
    ushort_t* ob  = (ushort_t*)(ws + 26 * MB);
    ushort_t* xb  = (ushort_t*)(ws + 34 * MB);
    ushort_t* wqb = (ushort_t*)(ws + 42 * MB);

    prep<<<3072, 256, 0, stream>>>(x, w_qkv, w_out, xb, wqb, wob);
    gemm_qkv_mfma<<<dim3(24, 32), 256, 0, stream>>>(xb, wqb, qb, kb, vt, cosb, sinb);
    attn_mfma<<<dim3(16, 2, 16), 256, 0, stream>>>(qb, kb, vt, ob);
    gemm_out_mfma<<<dim3(16, 32), 256, 0, stream>>>(ob, wob, out);
}